// Round 2
// baseline (1022.586 us; speedup 1.0000x reference)
//
#include <hip/hip_runtime.h>
#include <math.h>

#define BLOCK 256
#define EGRID 2048                 // edge-parallel / bulk kernels
#define SG    512                  // scan/sort kernels (fixed structure)
#define NTHE (EGRID*BLOCK)
#define NWVE (NTHE/64)
#define INF_ 0x7fffffff
#define TB   6000                  // bitset-tail threshold (capacity ~7155)
#define AWMAX 224
#define TBCAP 7168                 // AWMAX*32
#define DENSE_ITERS 6

struct KParams {
  const float* x;
  const int*   ei;
  const float* w;
  const float* bb;
  float* out;
  int n, e, d, out_size;
  int* ws;
  long long ws_ints;
};

struct Lay {
  float* score; int *ks1,*cursor;
  int *keyA,*idxA,*keyB,*idxB,*lrank;
  int *rank,*mr,*t1,*mis,*mm,*misPre,*r2c,*clus,*colPtr,*rowPtr;
  unsigned *bh,*dtot,*dbase,*btot,*bbase;
  int *cnts,*colSrc,*rowDst,*pairCnt;
  long long unionBase;
};

__device__ __host__ inline Lay mklay(int* ws, int n, int e) {
  Lay L;
  L.score=(float*)ws;
  L.ks1   = ws + (size_t)1*n;
  L.cursor= ws + (size_t)2*n;          // CSR cursor -> nodeIdx (tail)
  L.keyA  = ws + (size_t)3*n;          // sort key -> active list parity 0
  L.idxA  = ws + (size_t)4*n;          // sort payload: idxA[i]=node with rank i
  L.keyB  = ws + (size_t)5*n;          // sort key -> active list parity 1
  L.idxB  = ws + (size_t)6*n;
  L.lrank = ws + (size_t)7*n;          // sort tmp -> tail sorted list S
  L.rank  = ws + (size_t)8*n;
  L.mr    = ws + (size_t)9*n;          // tmin temp; final khop result
  L.t1    = ws + (size_t)10*n;         // tor temp; tcomp prefix; fin temp
  L.mis   = ws + (size_t)11*n;
  L.mm    = ws + (size_t)12*n;         // a[] = active?rank:INF; then fin0 output
  L.misPre= ws + (size_t)13*n;         // post misPre
  L.r2c   = ws + (size_t)14*n;
  L.clus  = ws + (size_t)15*n;
  L.colPtr= ws + (size_t)16*n;         // n+1
  L.rowPtr= ws + (size_t)17*n + 64;    // unused (layout keep)
  int* sm = ws + (size_t)18*n + 128;
  L.bh    = (unsigned*)sm;             // 256*SG
  L.dtot  = L.bh + 256*SG;             // 256
  L.dbase = L.dtot + 256;              // 256 (unused now)
  L.btot  = L.dbase + 256;             // SG
  L.bbase = L.btot + SG;               // SG (unused now)
  L.cnts  = (int*)(L.bbase + SG);      // 16
  L.unionBase = 18ll*n + 128 + 256ll*SG + 512 + 2ll*SG + 16;
  L.colSrc  = ws + L.unionBase;        // e ints (in-CSR)
  L.rowDst  = L.colSrc + e;            // e ints -> tail bitset rows (bs)
  L.pairCnt = ws + L.unionBase;        // M*M ints (aliased, post-loop)
  return L;
}

// ---- unrolled gather reducers ----
__device__ inline int gmin_(const int* __restrict__ s, const int* __restrict__ val,
                            int p, int pe, int m) {
  for (; p+3 < pe; p += 4) {
    int a0=s[p],a1=s[p+1],a2=s[p+2],a3=s[p+3];
    int t0=val[a0],t1=val[a1],t2=val[a2],t3=val[a3];
    t0=min(t0,t1); t2=min(t2,t3); t0=min(t0,t2); if (t0<m) m=t0;
  }
  for (; p<pe; ++p){ int t=val[s[p]]; if (t<m) m=t; }
  return m;
}
__device__ inline int gor_(const int* __restrict__ s, const int* __restrict__ val,
                           int p, int pe, int m) {
  for (; p+3 < pe; p += 4) m |= val[s[p]] | val[s[p+1]] | val[s[p+2]] | val[s[p+3]];
  for (; p<pe; ++p) m |= val[s[p]];
  return m;
}
__device__ inline int gsum_(const int* __restrict__ s, const int* __restrict__ val,
                            int p, int pe, int m) {
  for (; p+3 < pe; p += 4) m += val[s[p]] + val[s[p+1]] + val[s[p+2]] + val[s[p+3]];
  for (; p<pe; ++p) m += val[s[p]];
  return m;
}

// sum of btot[0..upto) within a 256-thread block (barrier-protected shared reuse)
__device__ inline int btotPrefix(const unsigned* btot, int upto) {
  __shared__ int red[256];
  int tid = threadIdx.x;
  int partial = 0;
  for (int idx = tid; idx < upto; idx += 256) partial += (int)btot[idx];
  __syncthreads();
  red[tid] = partial; __syncthreads();
  for (int off = 128; off > 0; off >>= 1) { if (tid < off) red[tid] += red[tid+off]; __syncthreads(); }
  int r = red[0]; __syncthreads();
  return r;
}

// ---------------- phase kernels ----------------
__global__ __launch_bounds__(BLOCK) void k_score(KParams P) {
  Lay L = mklay(P.ws, P.n, P.e);
  int gid = blockIdx.x*BLOCK + threadIdx.x;
  int lane = gid & 63, gwv = gid >> 6;
  int d4 = P.d >> 2;
  double bconst = (double)P.bb[0];
  const float4* w4 = (const float4*)P.w;
  for (int v = gwv; v < P.n; v += NWVE) {
    const float4* xr = (const float4*)(P.x + (size_t)v*P.d);
    double s = 0.0;
    for (int q = lane; q < d4; q += 64) {
      float4 xv = xr[q], wv = w4[q];
      s += (double)xv.x*wv.x + (double)xv.y*wv.y + (double)xv.z*wv.z + (double)xv.w*wv.w;
    }
    for (int off = 32; off > 0; off >>= 1) s += __shfl_down(s, off);
    if (lane == 0) L.score[v] = (float)(1.0/(1.0+exp(-(s+bconst))));
  }
  for (int v = gid; v < P.n; v += NTHE) L.ks1[v] = 0;
}

__global__ __launch_bounds__(BLOCK) void k_degree(KParams P) {
  Lay L = mklay(P.ws, P.n, P.e);
  const int* col = P.ei + P.e;
  int gid = blockIdx.x*BLOCK + threadIdx.x;
  for (int j = gid; j < P.e; j += NTHE) atomicAdd(&L.ks1[col[j]], 1);
}

__global__ __launch_bounds__(BLOCK) void k_scan1(KParams P) {
  Lay L = mklay(P.ws, P.n, P.e);
  __shared__ int lds[256];
  int tid = threadIdx.x, bid = blockIdx.x;
  int chunk = (P.n + SG - 1)/SG;
  int ig = bid*chunk + tid;
  bool valid = (tid < chunk) && (ig < P.n);
  int v2 = valid ? L.ks1[ig] : 0;
  lds[tid] = v2; __syncthreads();
  for (int off = 1; off < 256; off <<= 1) {
    int t = (tid >= off) ? lds[tid-off] : 0; __syncthreads();
    lds[tid] += t; __syncthreads();
  }
  if (valid) L.colPtr[ig] = lds[tid] - v2;
  if (tid == 0) L.btot[bid] = (unsigned)lds[255];
}

// colPtr += prefix(btot); cursor=colPtr; ks1+=1  (btot scan folded in)
__global__ __launch_bounds__(BLOCK) void k_scan3(KParams P) {
  Lay L = mklay(P.ws, P.n, P.e);
  int tid = threadIdx.x, bid = blockIdx.x;
  int base = btotPrefix(L.btot, bid);
  int chunk = (P.n + SG - 1)/SG;
  int ig = bid*chunk + tid;
  if (tid < chunk && ig < P.n) {
    int cp = L.colPtr[ig] + base;
    L.colPtr[ig] = cp; L.cursor[ig] = cp; L.ks1[ig] += 1;
  }
  if (bid == 0 && tid == 0) L.colPtr[P.n] = P.e;
}

__global__ __launch_bounds__(BLOCK) void k_csr(KParams P) {
  Lay L = mklay(P.ws, P.n, P.e);
  const int* row = P.ei; const int* col = P.ei + P.e;
  int gid = blockIdx.x*BLOCK + threadIdx.x;
  for (int j = gid; j < P.e; j += NTHE) {
    int pos = atomicAdd(&L.cursor[col[j]], 1);
    L.colSrc[pos] = row[j];
  }
}

__global__ __launch_bounds__(BLOCK) void k_keygen(KParams P) {
  Lay L = mklay(P.ws, P.n, P.e);
  int v = blockIdx.x*BLOCK + threadIdx.x;
  if (v >= P.n) return;
  int s = gsum_(L.colSrc, L.ks1, L.colPtr[v], L.colPtr[v+1], L.ks1[v]);
  float upd = L.score[v] / (float)s;
  unsigned u = __float_as_uint(upd);
  u = (u & 0x80000000u) ? (~u) : (u | 0x80000000u);
  ((unsigned*)L.keyA)[v] = ~u;
  ((unsigned*)L.idxA)[v] = (unsigned)v;
}

__global__ __launch_bounds__(BLOCK) void k_sort_local(KParams P, int pass) {
  Lay L = mklay(P.ws, P.n, P.e);
  __shared__ int ldsH[1024];
  int tid = threadIdx.x, bid = blockIdx.x, lane = tid & 63, wib = tid >> 6;
  unsigned* sk = (pass & 1) ? (unsigned*)L.keyB : (unsigned*)L.keyA;
  int shift = pass*8;
  for (int i = tid; i < 1024; i += BLOCK) ldsH[i] = 0;
  __syncthreads();
  int chunk = (P.n + SG - 1)/SG;
  int ig = bid*chunk + tid;
  bool valid = (tid < chunk) && (ig < P.n);
  int dig = 0;
  if (valid) dig = (int)((sk[ig] >> shift) & 255u);
  unsigned long long mmask = __ballot(valid);
  for (int b = 0; b < 8; ++b) {
    unsigned long long bm = __ballot((dig >> b) & 1);
    mmask &= ((dig >> b) & 1) ? bm : ~bm;
  }
  int lp = 0;
  if (valid) {
    lp = __popcll(mmask & ((1ull << lane) - 1ull));
    if (lp == 0) ldsH[wib*256 + dig] = __popcll(mmask);
  }
  __syncthreads();
  if (tid < 256) {
    int c0=ldsH[tid], c1=ldsH[256+tid], c2=ldsH[512+tid], c3=ldsH[768+tid];
    ldsH[tid]=0; ldsH[256+tid]=c0; ldsH[512+tid]=c0+c1; ldsH[768+tid]=c0+c1+c2;
    L.bh[(size_t)tid*SG + bid] = (unsigned)(c0+c1+c2+c3);
  }
  __syncthreads();
  if (valid) ((unsigned*)L.lrank)[ig] = (unsigned)(ldsH[wib*256 + dig] + lp);
}

__global__ __launch_bounds__(BLOCK) void k_sort_scan1(KParams P) {
  Lay L = mklay(P.ws, P.n, P.e);
  int g = blockIdx.x*BLOCK + threadIdx.x;
  int dg = g >> 6, lane = g & 63;
  if (dg >= 256) return;
  unsigned running = 0;
  for (int r = 0; r < SG/64; ++r) {
    unsigned v = L.bh[(size_t)dg*SG + r*64 + lane];
    unsigned incl = v;
    for (int off = 1; off < 64; off <<= 1) { unsigned t = __shfl_up(incl, off); if (lane >= off) incl += t; }
    L.bh[(size_t)dg*SG + r*64 + lane] = incl - v + running;
    running += __shfl(incl, 63);
  }
  if (lane == 0) L.dtot[dg] = running;
}

// scatter with in-block dbase recompute (scanD folded in)
__global__ __launch_bounds__(BLOCK) void k_sort_scatter(KParams P, int pass) {
  Lay L = mklay(P.ws, P.n, P.e);
  __shared__ unsigned sdb[256];
  unsigned *sk,*si,*dk,*di;
  if (pass & 1) { sk=(unsigned*)L.keyB; si=(unsigned*)L.idxB; dk=(unsigned*)L.keyA; di=(unsigned*)L.idxA; }
  else          { sk=(unsigned*)L.keyA; si=(unsigned*)L.idxA; dk=(unsigned*)L.keyB; di=(unsigned*)L.idxB; }
  int tid = threadIdx.x, bid = blockIdx.x;
  unsigned myv = L.dtot[tid];
  sdb[tid] = myv; __syncthreads();
  for (int off = 1; off < 256; off <<= 1) {
    unsigned t = (tid >= off) ? sdb[tid-off] : 0u; __syncthreads();
    sdb[tid] += t; __syncthreads();
  }
  unsigned excl = sdb[tid] - myv; __syncthreads();
  sdb[tid] = excl; __syncthreads();
  int chunk = (P.n + SG - 1)/SG;
  int ig = bid*chunk + tid;
  if (tid < chunk && ig < P.n) {
    unsigned key = sk[ig];
    int dig = (int)((key >> (pass*8)) & 255u);
    unsigned pos = sdb[dig] + L.bh[(size_t)dig*SG + bid] + ((unsigned*)L.lrank)[ig];
    dk[pos] = key; di[pos] = si[ig];
  }
}

__global__ __launch_bounds__(BLOCK) void k_rankinit(KParams P) {
  Lay L = mklay(P.ws, P.n, P.e);
  int i = blockIdx.x*BLOCK + threadIdx.x;
  if (blockIdx.x == 0 && threadIdx.x == 0) {
    L.cnts[4] = P.n;   // A for parity 0
    L.cnts[5] = 0;
  }
  if (i >= P.n) return;
  int v = (int)((unsigned*)L.idxA)[i];
  L.rank[v] = i;
  L.mm[v] = i;        // a[] = rank (all active)
  L.mis[v] = 0;
}

// ---- dense KMIS iterations (static parity = t&1) ----
__global__ __launch_bounds__(BLOCK) void k_dmin(KParams P, int t) {
  Lay L = mklay(P.ws, P.n, P.e);
  if (L.cnts[4+(t&1)] <= TB) return;
  int w = blockIdx.x*BLOCK + threadIdx.x;
  if (w >= P.n) return;
  L.mr[w] = gmin_(L.colSrc, L.mm, L.colPtr[w], L.colPtr[w+1], L.mm[w]);
}
__global__ __launch_bounds__(BLOCK) void k_dsel(KParams P, int t) {
  Lay L = mklay(P.ws, P.n, P.e);
  int q = t & 1;
  int A = L.cnts[4+q];
  if (A <= TB) return;
  int i = blockIdx.x*BLOCK + threadIdx.x;
  if (i >= A) return;
  int v = (t == 0) ? i : (q ? L.keyB : L.keyA)[i];
  int m2 = gmin_(L.colSrc, L.mr, L.colPtr[v], L.colPtr[v+1], L.mr[v]);
  if (L.rank[v] == m2) L.mis[v] = 1;
}
__global__ __launch_bounds__(BLOCK) void k_dor(KParams P, int t) {
  Lay L = mklay(P.ws, P.n, P.e);
  int q = t & 1;
  if (L.cnts[4+q] <= TB) return;
  int w = blockIdx.x*BLOCK + threadIdx.x;
  if (blockIdx.x == 0 && threadIdx.x == 0) L.cnts[4+(1-q)] = 0;
  if (w >= P.n) return;
  L.t1[w] = gor_(L.colSrc, L.mis, L.colPtr[w], L.colPtr[w+1], L.mis[w]);
}
__global__ __launch_bounds__(BLOCK) void k_drb(KParams P, int t) {
  Lay L = mklay(P.ws, P.n, P.e);
  int q = t & 1;
  int A = L.cnts[4+q];
  int* act  = (t == 0) ? (int*)0 : (q ? L.keyB : L.keyA);
  int* nact = q ? L.keyA : L.keyB;
  int gid = blockIdx.x*BLOCK + threadIdx.x;
  if (A <= TB) {                       // copy mode: keep parity flipping static
    for (int i = gid; i < A; i += (P.n + BLOCK - 1)/BLOCK*BLOCK) nact[i] = act[i];
    if (gid == 0) L.cnts[4+(1-q)] = A;
    return;
  }
  int lane = threadIdx.x & 63;
  bool aliveF = false; int v = 0;
  if (gid < A) {
    v = (t == 0) ? gid : act[gid];
    int dead = gor_(L.colSrc, L.t1, L.colPtr[v], L.colPtr[v+1], L.t1[v]);
    if (dead) L.mm[v] = INF_; else aliveF = true;
  }
  unsigned long long mk = __ballot(aliveF);
  int cntw = __popcll(mk);
  if (cntw) {
    int fl = __ffsll((unsigned long long)mk) - 1;
    int base = 0;
    if (lane == fl) base = atomicAdd(&L.cnts[4+(1-q)], cntw);
    base = __shfl(base, fl);
    if (aliveF) nact[base + __popcll(mk & ((1ull<<lane)-1ull))] = v;
  }
}

// ---- tail: compact survivors in rank order (flags via mm != INF over idxA) ----
__global__ __launch_bounds__(BLOCK) void k_tcomp1(KParams P) {
  Lay L = mklay(P.ws, P.n, P.e);
  __shared__ int lds[256];
  int tid = threadIdx.x, bid = blockIdx.x;
  int chunk = (P.n + SG - 1)/SG;
  int ig = bid*chunk + tid;
  bool valid = (tid < chunk) && (ig < P.n);
  int f = 0;
  if (valid) { int v = (int)((unsigned*)L.idxA)[ig]; f = (L.mm[v] != INF_) ? 1 : 0; }
  lds[tid] = f; __syncthreads();
  for (int off = 1; off < 256; off <<= 1) {
    int t = (tid >= off) ? lds[tid-off] : 0; __syncthreads();
    lds[tid] += t; __syncthreads();
  }
  if (valid) L.t1[ig] = lds[tid] - f;
  if (tid == 0) L.btot[bid] = (unsigned)lds[255];
}
// S[pos]=v ordered by rank; cursor[v]=pos or -1; zero bs (+trans if it fits)
__global__ __launch_bounds__(BLOCK) void k_tcomp3(KParams P) {
  Lay L = mklay(P.ws, P.n, P.e);
  int tid = threadIdx.x, bid = blockIdx.x;
  int base = btotPrefix(L.btot, bid);
  int chunk = (P.n + SG - 1)/SG;
  int ig = bid*chunk + tid;
  if (tid < chunk && ig < P.n) {
    int v = (int)((unsigned*)L.idxA)[ig];
    if (L.mm[v] != INF_) {
      int pos = L.t1[ig] + base;
      L.lrank[pos] = v;          // S
      L.cursor[v] = pos;         // nodeIdx
    } else L.cursor[v] = -1;
  }
  int A = L.cnts[4];
  if (A > 0) {
    int AW = (A + 31) >> 5;
    int AWP = (AW + 3) & ~3;     // 16B-padded row stride
    unsigned* bs = (unsigned*)L.rowDst;
    long long tot = (long long)A * AWP;
    for (long long idx = (long long)bid*BLOCK + tid; idx < tot; idx += (long long)SG*BLOCK) bs[idx] = 0u;
    bool transOk = (L.unionBase + 2ll*P.e + tot <= P.ws_ints);
    if (transOk) {
      unsigned* tr = (unsigned*)(P.ws + L.unionBase + 2ll*P.e);
      for (long long idx = (long long)bid*BLOCK + tid; idx < tot; idx += (long long)SG*BLOCK) tr[idx] = 0u;
    }
  }
}
// build in2closed source bitsets (+transpose), wave per row
__global__ __launch_bounds__(BLOCK) void k_tbuild(KParams P) {
  Lay L = mklay(P.ws, P.n, P.e);
  int A = L.cnts[4];
  if (A <= 0) return;
  int AW = (A + 31) >> 5;
  int AWP = (AW + 3) & ~3;
  unsigned* bs = (unsigned*)L.rowDst;
  bool transOk = (L.unionBase + 2ll*P.e + (long long)A*AWP <= P.ws_ints);
  unsigned* tr = transOk ? (unsigned*)(P.ws + L.unionBase + 2ll*P.e) : (unsigned*)0;
  const int* __restrict__ cp = L.colPtr;
  const int* __restrict__ cs = L.colSrc;
  const int* __restrict__ nodeIdx = L.cursor;
  int gid = blockIdx.x*BLOCK + threadIdx.x;
  int lane = gid & 63, gwv = gid >> 6;
  int nW = (gridDim.x*BLOCK) >> 6;
  for (int i = gwv; i < A; i += nW) {
    int v = L.lrank[i];
    unsigned* row = bs + (size_t)i*AWP;
    unsigned ibit = 1u << (i & 31);
    int iw = i >> 5;
    if (lane == 0) {
      atomicOr(&row[iw], ibit);
      if (tr) atomicOr(&tr[(size_t)i*AWP + iw], ibit);
    }
    int p0 = cp[v], p1 = cp[v+1];
    for (int p = p0 + lane; p < p1; p += 64) {
      int u = cs[p];
      int j = nodeIdx[u];
      if (j >= 0) {
        atomicOr(&row[j >> 5], 1u << (j & 31));
        if (tr) atomicOr(&tr[(size_t)j*AWP + iw], ibit);
      }
      int p3 = cp[u+1];
      for (int p2 = cp[u]; p2 < p3; ++p2) {
        int w2 = cs[p2];
        int j2 = nodeIdx[w2];
        if (j2 >= 0) {
          atomicOr(&row[j2 >> 5], 1u << (j2 & 31));
          if (tr) atomicOr(&tr[(size_t)j2*AWP + iw], ibit);
        }
      }
    }
  }
}
// all MIS rounds in one 1024-thread block.
// ph1: witness caching — prefix words with row&alive==0 stay 0 forever
// (alive only shrinks), so each row resumes at its cached blocker word.
// ph2: dead = union of trans[j] over selected j (exact rewrite of the
// "row intersects selected" kill rule); falls back to full row scans
// if the transpose didn't fit in workspace.
__global__ __launch_bounds__(1024) void k_trounds(KParams P) {
  Lay L = mklay(P.ws, P.n, P.e);
  __shared__ __align__(16) unsigned aliveW[AWMAX];
  __shared__ __align__(16) unsigned selW[AWMAX];
  __shared__ __align__(16) unsigned deadW[AWMAX];
  __shared__ int selList[TBCAP];
  __shared__ unsigned char pw[TBCAP];
  __shared__ int scnt, selCnt;
  int A = L.cnts[4];
  if (A <= 0) return;
  int AW = (A + 31) >> 5;
  int AWP = (AW + 3) & ~3;
  const unsigned* __restrict__ bs = (const unsigned*)L.rowDst;
  bool transOk = (L.unionBase + 2ll*P.e + (long long)A*AWP <= P.ws_ints);
  const unsigned* __restrict__ tr = (const unsigned*)(P.ws + L.unionBase + 2ll*P.e);
  const int* __restrict__ S = L.lrank;
  int tid = threadIdx.x;
  for (int w = tid; w < AWP; w += 1024) {
    int base = w*32; int c = A - base;
    aliveW[w] = (c >= 32) ? 0xffffffffu : ((c > 0) ? ((1u << c) - 1u) : 0u);
  }
  for (int i = tid; i < A; i += 1024) pw[i] = 0;
  __syncthreads();
  for (int rounds = 0; rounds < 8192; ++rounds) {
    for (int w = tid; w < AWP; w += 1024) { selW[w] = 0u; deadW[w] = 0u; }
    if (tid == 0) { scnt = 0; selCnt = 0; }
    __syncthreads();
    // ph1: select alive i with no alive smaller-ranked in-2 source
    for (int i = tid; i < A; i += 1024) {
      if ((aliveW[i>>5] >> (i&31)) & 1u) {
        const unsigned* __restrict__ row = bs + (size_t)i*AWP;
        int wl = i >> 5;
        int g = pw[i];
        unsigned any = 0;
        while (g < wl) {
          any = row[g] & aliveW[g];
          if (any) break;
          ++g;                       // permanent: this word can never light up again
        }
        pw[i] = (unsigned char)g;
        if (!any && (i & 31)) any = row[wl] & aliveW[wl] & ((1u << (i&31)) - 1u);
        if (!any) {
          int sp = atomicAdd(&selCnt, 1);
          selList[sp] = i;
          atomicOr(&selW[i>>5], 1u << (i&31));
          L.mis[S[i]] = 1;
        }
      }
    }
    __syncthreads();
    int nsel = selCnt;
    if (nsel == 0) break;            // alive empty (defensive; min-alive is always selectable)
    int surv = 0;
    if (transOk) {
      // accumulate dead = OR of trans rows of selected, 4 q-slices per word
      int w = tid & 255, qs = tid >> 8;
      if (w < AW) {
        unsigned acc = 0;
        for (int q = qs; q < nsel; q += 4) acc |= tr[(size_t)selList[q]*AWP + w];
        if (acc) atomicOr(&deadW[w], acc);
      }
      __syncthreads();
      for (int w2 = tid; w2 < AW; w2 += 1024) {
        unsigned na = aliveW[w2] & ~deadW[w2];
        aliveW[w2] = na;
        surv += __popc(na);
      }
    } else {
      for (int i = tid; i < A; i += 1024) {
        if ((aliveW[i>>5] >> (i&31)) & 1u) {
          const uint4* __restrict__ r4 = (const uint4*)(bs + (size_t)i*AWP);
          const uint4* __restrict__ s4 = (const uint4*)selW;
          unsigned dead = 0;
          int ng = AWP >> 2;
          for (int g2 = 0; g2 < ng; ++g2) {
            uint4 a = r4[g2], sa = s4[g2];
            dead |= (a.x&sa.x)|(a.y&sa.y)|(a.z&sa.z)|(a.w&sa.w);
          }
          if (dead) atomicAnd(&aliveW[i>>5], ~(1u << (i&31)));
          else ++surv;
        }
      }
    }
    if (surv) atomicAdd(&scnt, surv);
    __syncthreads();
    int sc = scnt;
    __syncthreads();
    if (sc == 0) break;
  }
}

// ---- final khop_min; fin0 folded into scanM1 ----
__global__ __launch_bounds__(BLOCK) void k_scanM1(KParams P) {
  Lay L = mklay(P.ws, P.n, P.e);
  __shared__ int lds[256];
  int tid = threadIdx.x, bid = blockIdx.x;
  int chunk = (P.n + SG - 1)/SG;
  int ig = bid*chunk + tid;
  bool valid = (tid < chunk) && (ig < P.n);
  int v2 = 0;
  if (valid) {
    v2 = L.mis[ig];
    L.mm[ig] = v2 ? L.rank[ig] : P.n;   // fin0
  }
  lds[tid] = v2; __syncthreads();
  for (int off = 1; off < 256; off <<= 1) {
    int t = (tid >= off) ? lds[tid-off] : 0; __syncthreads();
    lds[tid] += t; __syncthreads();
  }
  if (valid) L.misPre[ig] = lds[tid] - v2;
  if (tid == 0) L.btot[bid] = (unsigned)lds[255];
}
__global__ __launch_bounds__(BLOCK) void k_fin1(KParams P) {
  Lay L = mklay(P.ws, P.n, P.e);
  int v = blockIdx.x*BLOCK + threadIdx.x;
  if (v >= P.n) return;
  L.t1[v] = gmin_(L.colSrc, L.mm, L.colPtr[v], L.colPtr[v+1], L.mm[v]);
}
__global__ __launch_bounds__(BLOCK) void k_fin2(KParams P) {
  Lay L = mklay(P.ws, P.n, P.e);
  int v = blockIdx.x*BLOCK + threadIdx.x;
  if (v >= P.n) return;
  L.mr[v] = gmin_(L.colSrc, L.t1, L.colPtr[v], L.colPtr[v+1], L.t1[v]);
}
// misPre += prefix(btot); r2c; cnts[2]=num_mis  (scanB folded)
__global__ __launch_bounds__(BLOCK) void k_scanM3(KParams P) {
  Lay L = mklay(P.ws, P.n, P.e);
  int tid = threadIdx.x, bid = blockIdx.x;
  int base = btotPrefix(L.btot, bid);
  int total = btotPrefix(L.btot, SG);
  int chunk = (P.n + SG - 1)/SG;
  int ig = bid*chunk + tid;
  if (tid < chunk && ig < P.n) {
    int p = L.misPre[ig] + base;
    L.misPre[ig] = p;
    if (L.mis[ig]) L.r2c[L.rank[ig]] = p;
  }
  if (bid == 0 && tid == 0) L.cnts[2] = total;
}

__global__ __launch_bounds__(BLOCK) void k_clus(KParams P) {
  Lay L = mklay(P.ws, P.n, P.e);
  int gid = blockIdx.x*BLOCK + threadIdx.x;
  int M = L.cnts[2];
  long long M2 = (long long)M*M;
  for (int v = gid; v < P.n; v += NTHE) {
    int r3 = L.mr[v];
    L.clus[v] = (r3 >= 0 && r3 < P.n) ? L.r2c[r3] : 0;
  }
  bool pairOk = (M > 0) && (M2 < 0x7fffffffll) && (L.unionBase + M2 <= P.ws_ints);
  if (pairOk) {
    int m2i = (int)M2;
    for (int i = gid; i < m2i; i += NTHE) L.pairCnt[i] = 0;
  }
}

__global__ __launch_bounds__(BLOCK) void k_pair(KParams P) {
  Lay L = mklay(P.ws, P.n, P.e);
  int M = L.cnts[2];
  long long M2 = (long long)M*M;
  bool pairOk = (M > 0) && (M2 < 0x7fffffffll) && (L.unionBase + M2 <= P.ws_ints);
  if (!pairOk) return;
  const int* row = P.ei; const int* col = P.ei + P.e;
  int gid = blockIdx.x*BLOCK + threadIdx.x;
  for (int j = gid; j < P.e; j += NTHE) {
    int a = L.clus[row[j]], b2 = L.clus[col[j]];
    atomicAdd(&L.pairCnt[a*M + b2], 1);
  }
}

__global__ __launch_bounds__(BLOCK) void k_keep1(KParams P) {
  Lay L = mklay(P.ws, P.n, P.e);
  __shared__ int lds[256];
  int tid = threadIdx.x, bid = blockIdx.x;
  int M = L.cnts[2];
  long long M2 = (long long)M*M;
  bool pairOk = (M > 0) && (M2 < 0x7fffffffll) && (L.unionBase + M2 <= P.ws_ints);
  int m2i = pairOk ? (int)M2 : 0;
  int chunkP = pairOk ? (m2i + SG - 1)/SG : 0;
  int pstart = bid*chunkP; if (pstart > m2i) pstart = m2i;
  int pend = pstart + chunkP; if (pend > m2i) pend = m2i;
  int localKeep = 0;
  for (int i = pstart + tid; i < pend; i += BLOCK) {
    int c = L.pairCnt[i];
    if (c > 0 && (i / M) != (i % M)) ++localKeep;
  }
  lds[tid] = localKeep; __syncthreads();
  for (int off = 128; off > 0; off >>= 1) { if (tid < off) lds[tid] += lds[tid+off]; __syncthreads(); }
  if (tid == 0) L.btot[bid] = (unsigned)lds[0];
}

__global__ __launch_bounds__(BLOCK) void k_edges(KParams P) {
  Lay L = mklay(P.ws, P.n, P.e);
  __shared__ int lds[256];
  int tid = threadIdx.x, bid = blockIdx.x;
  int M = L.cnts[2];
  long long M2 = (long long)M*M;
  bool pairOk = (M > 0) && (M2 < 0x7fffffffll) && (L.unionBase + M2 <= P.ws_ints);
  if (!pairOk) return;
  int base = btotPrefix(L.btot, bid);
  int EK = btotPrefix(L.btot, SG);
  int m2i = (int)M2;
  int chunkP = (m2i + SG - 1)/SG;
  int pstart = bid*chunkP; if (pstart > m2i) pstart = m2i;
  int pend = pstart + chunkP; if (pend > m2i) pend = m2i;
  size_t eBase = (size_t)M * (size_t)P.d;
  bool outOk = (eBase + 3ull*(size_t)EK <= (size_t)P.out_size);
  int running2 = base;
  for (int t0 = pstart; t0 < pend; t0 += BLOCK) {
    int i = t0 + tid;
    int c = 0, kept = 0, a = 0, b2 = 0;
    if (i < pend) {
      c = L.pairCnt[i];
      a = i / M; b2 = i % M;
      kept = (c > 0 && a != b2) ? 1 : 0;
    }
    lds[tid] = kept; __syncthreads();
    for (int off = 1; off < 256; off <<= 1) {
      int t = (tid >= off) ? lds[tid-off] : 0; __syncthreads();
      lds[tid] += t; __syncthreads();
    }
    int incl = lds[tid], tot = lds[255];
    if (kept && outOk) {
      int j2 = running2 + incl - 1;
      P.out[eBase + (size_t)j2] = (float)a;
      P.out[eBase + (size_t)EK + (size_t)j2] = (float)b2;
      P.out[eBase + 2ull*(size_t)EK + (size_t)j2] = (float)c;
    }
    running2 += tot;
    __syncthreads();
  }
}

__global__ __launch_bounds__(BLOCK) void k_xpool(KParams P) {
  Lay L = mklay(P.ws, P.n, P.e);
  int gid = blockIdx.x*BLOCK + threadIdx.x;
  int lane = gid & 63, gwv = gid >> 6;
  int M = L.cnts[2];
  int d4 = P.d >> 2;
  size_t eBase = (size_t)M * (size_t)P.d;
  if (eBase > (size_t)P.out_size) return;
  for (int v = gwv; v < P.n; v += NWVE) {
    if (L.mis[v]) {
      int p = L.misPre[v];
      float sc = L.score[v];
      const float4* xr = (const float4*)(P.x + (size_t)v*P.d);
      float4* outr = (float4*)P.out + (size_t)p*d4;
      for (int q = lane; q < d4; q += 64) {
        float4 xv = xr[q];
        outr[q] = make_float4(xv.x*sc, xv.y*sc, xv.z*sc, xv.w*sc);
      }
    }
  }
}

extern "C" void kernel_launch(void* const* d_in, const int* in_sizes, int n_in,
                              void* d_out, int out_size, void* d_ws, size_t ws_size,
                              hipStream_t stream) {
  KParams P;
  P.x  = (const float*)d_in[0];
  P.ei = (const int*)d_in[1];
  P.w  = (const float*)d_in[2];
  P.bb = (const float*)d_in[3];
  P.out = (float*)d_out;
  P.d = in_sizes[2];            // 256
  P.n = in_sizes[0] / P.d;      // 100000
  P.e = in_sizes[1] / 2;        // 1600000
  P.out_size = out_size;
  P.ws = (int*)d_ws;
  P.ws_ints = (long long)(ws_size / 4);
  const int nblk = (P.n + BLOCK - 1) / BLOCK;

  k_score <<<EGRID, BLOCK, 0, stream>>>(P);
  k_degree<<<EGRID, BLOCK, 0, stream>>>(P);
  k_scan1 <<<SG,    BLOCK, 0, stream>>>(P);
  k_scan3 <<<SG,    BLOCK, 0, stream>>>(P);
  k_csr   <<<EGRID, BLOCK, 0, stream>>>(P);
  k_keygen<<<nblk,  BLOCK, 0, stream>>>(P);
  for (int pass = 0; pass < 4; ++pass) {
    k_sort_local  <<<SG, BLOCK, 0, stream>>>(P, pass);
    k_sort_scan1  <<<64, BLOCK, 0, stream>>>(P);
    k_sort_scatter<<<SG, BLOCK, 0, stream>>>(P, pass);
  }
  k_rankinit<<<nblk, BLOCK, 0, stream>>>(P);
  for (int t = 0; t < DENSE_ITERS; ++t) {
    k_dmin <<<nblk, BLOCK, 0, stream>>>(P, t);
    k_dsel <<<nblk, BLOCK, 0, stream>>>(P, t);
    k_dor  <<<nblk, BLOCK, 0, stream>>>(P, t);
    k_drb  <<<nblk, BLOCK, 0, stream>>>(P, t);
  }
  k_tcomp1 <<<SG,   BLOCK, 0, stream>>>(P);
  k_tcomp3 <<<SG,   BLOCK, 0, stream>>>(P);
  k_tbuild <<<nblk, BLOCK, 0, stream>>>(P);
  k_trounds<<<1,    1024,  0, stream>>>(P);
  k_scanM1<<<SG, BLOCK, 0, stream>>>(P);
  k_fin1  <<<nblk, BLOCK, 0, stream>>>(P);
  k_fin2  <<<nblk, BLOCK, 0, stream>>>(P);
  k_scanM3<<<SG, BLOCK, 0, stream>>>(P);
  k_clus <<<EGRID, BLOCK, 0, stream>>>(P);
  k_pair <<<EGRID, BLOCK, 0, stream>>>(P);
  k_keep1<<<SG,    BLOCK, 0, stream>>>(P);
  k_edges<<<SG,    BLOCK, 0, stream>>>(P);
  k_xpool<<<EGRID, BLOCK, 0, stream>>>(P);
}

// Round 3
// 863.360 us; speedup vs baseline: 1.1844x; 1.1844x over previous
//
#include <hip/hip_runtime.h>
#include <math.h>

#define BLOCK 256
#define EGRID 2048                 // edge-parallel / bulk kernels
#define SG    512                  // scan/sort kernels (fixed structure)
#define NTHE (EGRID*BLOCK)
#define NWVE (NTHE/64)
#define INF_ 0x7fffffff
#define TB   6000                  // bitset-tail threshold (capacity ~7155)
#define AWMAX 224
#define TBCAP 7168                 // AWMAX*32
#define DENSE_ITERS 6

struct KParams {
  const float* x;
  const int*   ei;
  const float* w;
  const float* bb;
  float* out;
  int n, e, d, out_size;
  int* ws;
  long long ws_ints;
};

struct Lay {
  float* score; int *ks1,*cursor;
  int *keyA,*idxA,*keyB,*idxB,*lrank;
  int *rank,*mr,*t1,*mis,*mm,*misPre,*r2c,*clus,*colPtr,*rowPtr;
  unsigned *bh,*dtot,*dbase,*btot,*bbase;
  int *cnts,*colSrc,*rowDst,*pairCnt;
  long long unionBase;
};

__device__ __host__ inline Lay mklay(int* ws, int n, int e) {
  Lay L;
  L.score=(float*)ws;
  L.ks1   = ws + (size_t)1*n;
  L.cursor= ws + (size_t)2*n;          // CSR cursor -> nodeIdx (tail)
  L.keyA  = ws + (size_t)3*n;          // sort key -> active list parity 0
  L.idxA  = ws + (size_t)4*n;          // sort payload: idxA[i]=node with rank i
  L.keyB  = ws + (size_t)5*n;          // sort key -> active list parity 1
  L.idxB  = ws + (size_t)6*n;
  L.lrank = ws + (size_t)7*n;          // sort tmp -> tail sorted list S
  L.rank  = ws + (size_t)8*n;
  L.mr    = ws + (size_t)9*n;          // tmin temp; final khop result
  L.t1    = ws + (size_t)10*n;         // tor temp; tcomp prefix; fin temp
  L.mis   = ws + (size_t)11*n;
  L.mm    = ws + (size_t)12*n;         // a[] = active?rank:INF; then fin0 output
  L.misPre= ws + (size_t)13*n;         // post misPre
  L.r2c   = ws + (size_t)14*n;
  L.clus  = ws + (size_t)15*n;
  L.colPtr= ws + (size_t)16*n;         // n+1
  L.rowPtr= ws + (size_t)17*n + 64;    // unused (layout keep)
  int* sm = ws + (size_t)18*n + 128;
  L.bh    = (unsigned*)sm;             // 256*SG
  L.dtot  = L.bh + 256*SG;             // 256
  L.dbase = L.dtot + 256;              // 256 (unused now)
  L.btot  = L.dbase + 256;             // SG
  L.bbase = L.btot + SG;               // SG (unused now)
  L.cnts  = (int*)(L.bbase + SG);      // 16
  L.unionBase = 18ll*n + 128 + 256ll*SG + 512 + 2ll*SG + 16;
  L.colSrc  = ws + L.unionBase;        // e ints (in-CSR)
  L.rowDst  = L.colSrc + e;            // e ints -> tail bitset rows (bs)
  L.pairCnt = ws + L.unionBase;        // M*M ints (aliased, post-loop)
  return L;
}

// ---- unrolled gather reducers ----
__device__ inline int gmin_(const int* __restrict__ s, const int* __restrict__ val,
                            int p, int pe, int m) {
  for (; p+3 < pe; p += 4) {
    int a0=s[p],a1=s[p+1],a2=s[p+2],a3=s[p+3];
    int t0=val[a0],t1=val[a1],t2=val[a2],t3=val[a3];
    t0=min(t0,t1); t2=min(t2,t3); t0=min(t0,t2); if (t0<m) m=t0;
  }
  for (; p<pe; ++p){ int t=val[s[p]]; if (t<m) m=t; }
  return m;
}
__device__ inline int gor_(const int* __restrict__ s, const int* __restrict__ val,
                           int p, int pe, int m) {
  for (; p+3 < pe; p += 4) m |= val[s[p]] | val[s[p+1]] | val[s[p+2]] | val[s[p+3]];
  for (; p<pe; ++p) m |= val[s[p]];
  return m;
}
__device__ inline int gsum_(const int* __restrict__ s, const int* __restrict__ val,
                            int p, int pe, int m) {
  for (; p+3 < pe; p += 4) m += val[s[p]] + val[s[p+1]] + val[s[p+2]] + val[s[p+3]];
  for (; p<pe; ++p) m += val[s[p]];
  return m;
}

// sum of btot[0..upto) within a 256-thread block (barrier-protected shared reuse)
__device__ inline int btotPrefix(const unsigned* btot, int upto) {
  __shared__ int red[256];
  int tid = threadIdx.x;
  int partial = 0;
  for (int idx = tid; idx < upto; idx += 256) partial += (int)btot[idx];
  __syncthreads();
  red[tid] = partial; __syncthreads();
  for (int off = 128; off > 0; off >>= 1) { if (tid < off) red[tid] += red[tid+off]; __syncthreads(); }
  int r = red[0]; __syncthreads();
  return r;
}

// ---------------- phase kernels ----------------
__global__ __launch_bounds__(BLOCK) void k_score(KParams P) {
  Lay L = mklay(P.ws, P.n, P.e);
  int gid = blockIdx.x*BLOCK + threadIdx.x;
  int lane = gid & 63, gwv = gid >> 6;
  int d4 = P.d >> 2;
  double bconst = (double)P.bb[0];
  const float4* w4 = (const float4*)P.w;
  for (int v = gwv; v < P.n; v += NWVE) {
    const float4* xr = (const float4*)(P.x + (size_t)v*P.d);
    double s = 0.0;
    for (int q = lane; q < d4; q += 64) {
      float4 xv = xr[q], wv = w4[q];
      s += (double)xv.x*wv.x + (double)xv.y*wv.y + (double)xv.z*wv.z + (double)xv.w*wv.w;
    }
    for (int off = 32; off > 0; off >>= 1) s += __shfl_down(s, off);
    if (lane == 0) L.score[v] = (float)(1.0/(1.0+exp(-(s+bconst))));
  }
  for (int v = gid; v < P.n; v += NTHE) L.ks1[v] = 0;
}

__global__ __launch_bounds__(BLOCK) void k_degree(KParams P) {
  Lay L = mklay(P.ws, P.n, P.e);
  const int* col = P.ei + P.e;
  int gid = blockIdx.x*BLOCK + threadIdx.x;
  for (int j = gid; j < P.e; j += NTHE) atomicAdd(&L.ks1[col[j]], 1);
}

__global__ __launch_bounds__(BLOCK) void k_scan1(KParams P) {
  Lay L = mklay(P.ws, P.n, P.e);
  __shared__ int lds[256];
  int tid = threadIdx.x, bid = blockIdx.x;
  int chunk = (P.n + SG - 1)/SG;
  int ig = bid*chunk + tid;
  bool valid = (tid < chunk) && (ig < P.n);
  int v2 = valid ? L.ks1[ig] : 0;
  lds[tid] = v2; __syncthreads();
  for (int off = 1; off < 256; off <<= 1) {
    int t = (tid >= off) ? lds[tid-off] : 0; __syncthreads();
    lds[tid] += t; __syncthreads();
  }
  if (valid) L.colPtr[ig] = lds[tid] - v2;
  if (tid == 0) L.btot[bid] = (unsigned)lds[255];
}

// colPtr += prefix(btot); cursor=colPtr; ks1+=1  (btot scan folded in)
__global__ __launch_bounds__(BLOCK) void k_scan3(KParams P) {
  Lay L = mklay(P.ws, P.n, P.e);
  int tid = threadIdx.x, bid = blockIdx.x;
  int base = btotPrefix(L.btot, bid);
  int chunk = (P.n + SG - 1)/SG;
  int ig = bid*chunk + tid;
  if (tid < chunk && ig < P.n) {
    int cp = L.colPtr[ig] + base;
    L.colPtr[ig] = cp; L.cursor[ig] = cp; L.ks1[ig] += 1;
  }
  if (bid == 0 && tid == 0) L.colPtr[P.n] = P.e;
}

__global__ __launch_bounds__(BLOCK) void k_csr(KParams P) {
  Lay L = mklay(P.ws, P.n, P.e);
  const int* row = P.ei; const int* col = P.ei + P.e;
  int gid = blockIdx.x*BLOCK + threadIdx.x;
  for (int j = gid; j < P.e; j += NTHE) {
    int pos = atomicAdd(&L.cursor[col[j]], 1);
    L.colSrc[pos] = row[j];
  }
}

__global__ __launch_bounds__(BLOCK) void k_keygen(KParams P) {
  Lay L = mklay(P.ws, P.n, P.e);
  int v = blockIdx.x*BLOCK + threadIdx.x;
  if (v >= P.n) return;
  int s = gsum_(L.colSrc, L.ks1, L.colPtr[v], L.colPtr[v+1], L.ks1[v]);
  float upd = L.score[v] / (float)s;
  unsigned u = __float_as_uint(upd);
  u = (u & 0x80000000u) ? (~u) : (u | 0x80000000u);
  ((unsigned*)L.keyA)[v] = ~u;
  ((unsigned*)L.idxA)[v] = (unsigned)v;
}

__global__ __launch_bounds__(BLOCK) void k_sort_local(KParams P, int pass) {
  Lay L = mklay(P.ws, P.n, P.e);
  __shared__ int ldsH[1024];
  int tid = threadIdx.x, bid = blockIdx.x, lane = tid & 63, wib = tid >> 6;
  unsigned* sk = (pass & 1) ? (unsigned*)L.keyB : (unsigned*)L.keyA;
  int shift = pass*8;
  for (int i = tid; i < 1024; i += BLOCK) ldsH[i] = 0;
  __syncthreads();
  int chunk = (P.n + SG - 1)/SG;
  int ig = bid*chunk + tid;
  bool valid = (tid < chunk) && (ig < P.n);
  int dig = 0;
  if (valid) dig = (int)((sk[ig] >> shift) & 255u);
  unsigned long long mmask = __ballot(valid);
  for (int b = 0; b < 8; ++b) {
    unsigned long long bm = __ballot((dig >> b) & 1);
    mmask &= ((dig >> b) & 1) ? bm : ~bm;
  }
  int lp = 0;
  if (valid) {
    lp = __popcll(mmask & ((1ull << lane) - 1ull));
    if (lp == 0) ldsH[wib*256 + dig] = __popcll(mmask);
  }
  __syncthreads();
  if (tid < 256) {
    int c0=ldsH[tid], c1=ldsH[256+tid], c2=ldsH[512+tid], c3=ldsH[768+tid];
    ldsH[tid]=0; ldsH[256+tid]=c0; ldsH[512+tid]=c0+c1; ldsH[768+tid]=c0+c1+c2;
    L.bh[(size_t)tid*SG + bid] = (unsigned)(c0+c1+c2+c3);
  }
  __syncthreads();
  if (valid) ((unsigned*)L.lrank)[ig] = (unsigned)(ldsH[wib*256 + dig] + lp);
}

__global__ __launch_bounds__(BLOCK) void k_sort_scan1(KParams P) {
  Lay L = mklay(P.ws, P.n, P.e);
  int g = blockIdx.x*BLOCK + threadIdx.x;
  int dg = g >> 6, lane = g & 63;
  if (dg >= 256) return;
  unsigned running = 0;
  for (int r = 0; r < SG/64; ++r) {
    unsigned v = L.bh[(size_t)dg*SG + r*64 + lane];
    unsigned incl = v;
    for (int off = 1; off < 64; off <<= 1) { unsigned t = __shfl_up(incl, off); if (lane >= off) incl += t; }
    L.bh[(size_t)dg*SG + r*64 + lane] = incl - v + running;
    running += __shfl(incl, 63);
  }
  if (lane == 0) L.dtot[dg] = running;
}

// scatter with in-block dbase recompute (scanD folded in)
__global__ __launch_bounds__(BLOCK) void k_sort_scatter(KParams P, int pass) {
  Lay L = mklay(P.ws, P.n, P.e);
  __shared__ unsigned sdb[256];
  unsigned *sk,*si,*dk,*di;
  if (pass & 1) { sk=(unsigned*)L.keyB; si=(unsigned*)L.idxB; dk=(unsigned*)L.keyA; di=(unsigned*)L.idxA; }
  else          { sk=(unsigned*)L.keyA; si=(unsigned*)L.idxA; dk=(unsigned*)L.keyB; di=(unsigned*)L.idxB; }
  int tid = threadIdx.x, bid = blockIdx.x;
  unsigned myv = L.dtot[tid];
  sdb[tid] = myv; __syncthreads();
  for (int off = 1; off < 256; off <<= 1) {
    unsigned t = (tid >= off) ? sdb[tid-off] : 0u; __syncthreads();
    sdb[tid] += t; __syncthreads();
  }
  unsigned excl = sdb[tid] - myv; __syncthreads();
  sdb[tid] = excl; __syncthreads();
  int chunk = (P.n + SG - 1)/SG;
  int ig = bid*chunk + tid;
  if (tid < chunk && ig < P.n) {
    unsigned key = sk[ig];
    int dig = (int)((key >> (pass*8)) & 255u);
    unsigned pos = sdb[dig] + L.bh[(size_t)dig*SG + bid] + ((unsigned*)L.lrank)[ig];
    dk[pos] = key; di[pos] = si[ig];
  }
}

__global__ __launch_bounds__(BLOCK) void k_rankinit(KParams P) {
  Lay L = mklay(P.ws, P.n, P.e);
  int i = blockIdx.x*BLOCK + threadIdx.x;
  if (blockIdx.x == 0 && threadIdx.x == 0) {
    L.cnts[4] = P.n;   // A for parity 0
    L.cnts[5] = 0;
  }
  if (i >= P.n) return;
  int v = (int)((unsigned*)L.idxA)[i];
  L.rank[v] = i;
  L.mm[v] = i;        // a[] = rank (all active)
  L.mis[v] = 0;
}

// ---- dense KMIS iterations (static parity = t&1) ----
__global__ __launch_bounds__(BLOCK) void k_dmin(KParams P, int t) {
  Lay L = mklay(P.ws, P.n, P.e);
  if (L.cnts[4+(t&1)] <= TB) return;
  int w = blockIdx.x*BLOCK + threadIdx.x;
  if (w >= P.n) return;
  L.mr[w] = gmin_(L.colSrc, L.mm, L.colPtr[w], L.colPtr[w+1], L.mm[w]);
}
__global__ __launch_bounds__(BLOCK) void k_dsel(KParams P, int t) {
  Lay L = mklay(P.ws, P.n, P.e);
  int q = t & 1;
  int A = L.cnts[4+q];
  if (A <= TB) return;
  int i = blockIdx.x*BLOCK + threadIdx.x;
  if (i >= A) return;
  int v = (t == 0) ? i : (q ? L.keyB : L.keyA)[i];
  int m2 = gmin_(L.colSrc, L.mr, L.colPtr[v], L.colPtr[v+1], L.mr[v]);
  if (L.rank[v] == m2) L.mis[v] = 1;
}
__global__ __launch_bounds__(BLOCK) void k_dor(KParams P, int t) {
  Lay L = mklay(P.ws, P.n, P.e);
  int q = t & 1;
  if (L.cnts[4+q] <= TB) return;
  int w = blockIdx.x*BLOCK + threadIdx.x;
  if (blockIdx.x == 0 && threadIdx.x == 0) L.cnts[4+(1-q)] = 0;
  if (w >= P.n) return;
  L.t1[w] = gor_(L.colSrc, L.mis, L.colPtr[w], L.colPtr[w+1], L.mis[w]);
}
__global__ __launch_bounds__(BLOCK) void k_drb(KParams P, int t) {
  Lay L = mklay(P.ws, P.n, P.e);
  int q = t & 1;
  int A = L.cnts[4+q];
  int* act  = (t == 0) ? (int*)0 : (q ? L.keyB : L.keyA);
  int* nact = q ? L.keyA : L.keyB;
  int gid = blockIdx.x*BLOCK + threadIdx.x;
  if (A <= TB) {                       // copy mode: keep parity flipping static
    for (int i = gid; i < A; i += (P.n + BLOCK - 1)/BLOCK*BLOCK) nact[i] = act[i];
    if (gid == 0) L.cnts[4+(1-q)] = A;
    return;
  }
  int lane = threadIdx.x & 63;
  bool aliveF = false; int v = 0;
  if (gid < A) {
    v = (t == 0) ? gid : act[gid];
    int dead = gor_(L.colSrc, L.t1, L.colPtr[v], L.colPtr[v+1], L.t1[v]);
    if (dead) L.mm[v] = INF_; else aliveF = true;
  }
  unsigned long long mk = __ballot(aliveF);
  int cntw = __popcll(mk);
  if (cntw) {
    int fl = __ffsll((unsigned long long)mk) - 1;
    int base = 0;
    if (lane == fl) base = atomicAdd(&L.cnts[4+(1-q)], cntw);
    base = __shfl(base, fl);
    if (aliveF) nact[base + __popcll(mk & ((1ull<<lane)-1ull))] = v;
  }
}

// ---- tail: compact survivors in rank order (flags via mm != INF over idxA) ----
__global__ __launch_bounds__(BLOCK) void k_tcomp1(KParams P) {
  Lay L = mklay(P.ws, P.n, P.e);
  __shared__ int lds[256];
  int tid = threadIdx.x, bid = blockIdx.x;
  int chunk = (P.n + SG - 1)/SG;
  int ig = bid*chunk + tid;
  bool valid = (tid < chunk) && (ig < P.n);
  int f = 0;
  if (valid) { int v = (int)((unsigned*)L.idxA)[ig]; f = (L.mm[v] != INF_) ? 1 : 0; }
  lds[tid] = f; __syncthreads();
  for (int off = 1; off < 256; off <<= 1) {
    int t = (tid >= off) ? lds[tid-off] : 0; __syncthreads();
    lds[tid] += t; __syncthreads();
  }
  if (valid) L.t1[ig] = lds[tid] - f;
  if (tid == 0) L.btot[bid] = (unsigned)lds[255];
}
// S[pos]=v ordered by rank; cursor[v]=pos or -1; zero bs (+trans if it fits)
__global__ __launch_bounds__(BLOCK) void k_tcomp3(KParams P) {
  Lay L = mklay(P.ws, P.n, P.e);
  int tid = threadIdx.x, bid = blockIdx.x;
  int base = btotPrefix(L.btot, bid);
  int chunk = (P.n + SG - 1)/SG;
  int ig = bid*chunk + tid;
  if (tid < chunk && ig < P.n) {
    int v = (int)((unsigned*)L.idxA)[ig];
    if (L.mm[v] != INF_) {
      int pos = L.t1[ig] + base;
      L.lrank[pos] = v;          // S
      L.cursor[v] = pos;         // nodeIdx
    } else L.cursor[v] = -1;
  }
  int A = L.cnts[4];
  if (A > 0) {
    int AW = (A + 31) >> 5;
    int AWP = (AW + 3) & ~3;     // 16B-padded row stride
    unsigned* bs = (unsigned*)L.rowDst;
    long long tot = (long long)A * AWP;
    for (long long idx = (long long)bid*BLOCK + tid; idx < tot; idx += (long long)SG*BLOCK) bs[idx] = 0u;
    bool transOk = (L.unionBase + 2ll*P.e + tot <= P.ws_ints);
    if (transOk) {
      unsigned* tr = (unsigned*)(P.ws + L.unionBase + 2ll*P.e);
      for (long long idx = (long long)bid*BLOCK + tid; idx < tot; idx += (long long)SG*BLOCK) tr[idx] = 0u;
    }
  }
}
// build in2closed source bitsets (+transpose), wave per row
__global__ __launch_bounds__(BLOCK) void k_tbuild(KParams P) {
  Lay L = mklay(P.ws, P.n, P.e);
  int A = L.cnts[4];
  if (A <= 0) return;
  int AW = (A + 31) >> 5;
  int AWP = (AW + 3) & ~3;
  unsigned* bs = (unsigned*)L.rowDst;
  bool transOk = (L.unionBase + 2ll*P.e + (long long)A*AWP <= P.ws_ints);
  unsigned* tr = transOk ? (unsigned*)(P.ws + L.unionBase + 2ll*P.e) : (unsigned*)0;
  const int* __restrict__ cp = L.colPtr;
  const int* __restrict__ cs = L.colSrc;
  const int* __restrict__ nodeIdx = L.cursor;
  int gid = blockIdx.x*BLOCK + threadIdx.x;
  int lane = gid & 63, gwv = gid >> 6;
  int nW = (gridDim.x*BLOCK) >> 6;
  for (int i = gwv; i < A; i += nW) {
    int v = L.lrank[i];
    unsigned* row = bs + (size_t)i*AWP;
    unsigned ibit = 1u << (i & 31);
    int iw = i >> 5;
    if (lane == 0) {
      atomicOr(&row[iw], ibit);
      if (tr) atomicOr(&tr[(size_t)i*AWP + iw], ibit);
    }
    int p0 = cp[v], p1 = cp[v+1];
    for (int p = p0 + lane; p < p1; p += 64) {
      int u = cs[p];
      int j = nodeIdx[u];
      if (j >= 0) {
        atomicOr(&row[j >> 5], 1u << (j & 31));
        if (tr) atomicOr(&tr[(size_t)j*AWP + iw], ibit);
      }
      int p3 = cp[u+1];
      for (int p2 = cp[u]; p2 < p3; ++p2) {
        int w2 = cs[p2];
        int j2 = nodeIdx[w2];
        if (j2 >= 0) {
          atomicOr(&row[j2 >> 5], 1u << (j2 & 31));
          if (tr) atomicOr(&tr[(size_t)j2*AWP + iw], ibit);
        }
      }
    }
  }
}
// all MIS rounds in one 1024-thread block.
// ph1: pipelined 2x-uint4 granule scan (R0 structure) + GRANULE-level witness
// cache: pw[i] = first granule whose row&alive may be nonzero; granules below
// it are permanently zero (alive only shrinks), so each round resumes there.
// ph2: dead = union of trans rows of selected (exact rewrite of the kill rule);
// falls back to breakless full row scans if the transpose didn't fit.
__global__ __launch_bounds__(1024) void k_trounds(KParams P) {
  Lay L = mklay(P.ws, P.n, P.e);
  __shared__ __align__(16) unsigned aliveW[AWMAX];
  __shared__ __align__(16) unsigned selW[AWMAX];
  __shared__ __align__(16) unsigned deadW[AWMAX];
  __shared__ int selList[TBCAP];
  __shared__ unsigned char pw[TBCAP];
  __shared__ int scnt, selCnt;
  int A = L.cnts[4];
  if (A <= 0) return;
  int AW = (A + 31) >> 5;
  int AWP = (AW + 3) & ~3;
  const unsigned* __restrict__ bs = (const unsigned*)L.rowDst;
  bool transOk = (L.unionBase + 2ll*P.e + (long long)A*AWP <= P.ws_ints);
  const unsigned* __restrict__ tr = (const unsigned*)(P.ws + L.unionBase + 2ll*P.e);
  const int* __restrict__ S = L.lrank;
  const uint4* __restrict__ a4 = (const uint4*)aliveW;
  int tid = threadIdx.x;
  for (int w = tid; w < AWP; w += 1024) {
    int base = w*32; int c = A - base;
    aliveW[w] = (c >= 32) ? 0xffffffffu : ((c > 0) ? ((1u << c) - 1u) : 0u);
  }
  for (int i = tid; i < A; i += 1024) pw[i] = 0;
  __syncthreads();
  for (int rounds = 0; rounds < 8192; ++rounds) {
    for (int w = tid; w < AWP; w += 1024) { selW[w] = 0u; deadW[w] = 0u; }
    if (tid == 0) { scnt = 0; selCnt = 0; }
    __syncthreads();
    // ph1: select alive i with no alive smaller-ranked in-2 source
    for (int i = tid; i < A; i += 1024) {
      if ((aliveW[i>>5] >> (i&31)) & 1u) {
        const unsigned* __restrict__ row = bs + (size_t)i*AWP;
        const uint4* __restrict__ r4 = (const uint4*)row;
        int wl = i >> 5;
        int nf = wl >> 2;                 // full granules strictly below word wl
        int g = (int)pw[i];
        unsigned any = 0;
        for (; g + 2 <= nf; g += 2) {     // 2x uint4 in flight, granule-level resolve
          uint4 a = r4[g],   b = r4[g+1];
          uint4 av = a4[g],  bv = a4[g+1];
          unsigned r0 = (a.x&av.x)|(a.y&av.y)|(a.z&av.z)|(a.w&av.w);
          unsigned r1 = (b.x&bv.x)|(b.y&bv.y)|(b.z&bv.z)|(b.w&bv.w);
          if (r0 | r1) { any = 1; if (!r0) ++g; break; }   // advance past verified-zero granule
        }
        if (!any && g < nf) {
          uint4 a = r4[g]; uint4 av = a4[g];
          unsigned r0 = (a.x&av.x)|(a.y&av.y)|(a.z&av.z)|(a.w&av.w);
          if (r0) any = 1; else ++g;
        }
        pw[i] = (unsigned char)g;         // granules < g are permanently dead
        if (!any) {
          for (int w2 = nf << 2; w2 < wl; ++w2) any |= row[w2] & aliveW[w2];
          if (!any && (i & 31)) any = row[wl] & aliveW[wl] & ((1u << (i&31)) - 1u);
        }
        if (!any) {
          int sp = atomicAdd(&selCnt, 1);
          selList[sp] = i;
          atomicOr(&selW[i>>5], 1u << (i&31));
          L.mis[S[i]] = 1;
        }
      }
    }
    __syncthreads();
    int nsel = selCnt;
    if (nsel == 0) break;            // alive empty (defensive; min-alive is always selectable)
    int surv = 0;
    if (transOk) {
      // accumulate dead = OR of trans rows of selected; coalesced (w = word, 4 q-slices)
      int w = tid & 255, qs = tid >> 8;
      if (w < AW) {
        unsigned acc = 0;
        for (int q = qs; q < nsel; q += 4) acc |= tr[(size_t)selList[q]*AWP + w];
        if (acc) atomicOr(&deadW[w], acc);
      }
      __syncthreads();
      for (int w2 = tid; w2 < AW; w2 += 1024) {
        unsigned na = aliveW[w2] & ~deadW[w2];
        aliveW[w2] = na;
        surv += __popc(na);
      }
    } else {
      for (int i = tid; i < A; i += 1024) {
        if ((aliveW[i>>5] >> (i&31)) & 1u) {
          const uint4* __restrict__ r4 = (const uint4*)(bs + (size_t)i*AWP);
          const uint4* __restrict__ s4 = (const uint4*)selW;
          unsigned dead = 0;
          int ng = AWP >> 2;
          for (int g2 = 0; g2 < ng; ++g2) {
            uint4 a = r4[g2], sa = s4[g2];
            dead |= (a.x&sa.x)|(a.y&sa.y)|(a.z&sa.z)|(a.w&sa.w);
          }
          if (dead) atomicAnd(&aliveW[i>>5], ~(1u << (i&31)));
          else ++surv;
        }
      }
    }
    if (surv) atomicAdd(&scnt, surv);
    __syncthreads();
    int sc = scnt;
    __syncthreads();
    if (sc == 0) break;
  }
}

// ---- final khop_min; fin0 folded into scanM1 ----
__global__ __launch_bounds__(BLOCK) void k_scanM1(KParams P) {
  Lay L = mklay(P.ws, P.n, P.e);
  __shared__ int lds[256];
  int tid = threadIdx.x, bid = blockIdx.x;
  int chunk = (P.n + SG - 1)/SG;
  int ig = bid*chunk + tid;
  bool valid = (tid < chunk) && (ig < P.n);
  int v2 = 0;
  if (valid) {
    v2 = L.mis[ig];
    L.mm[ig] = v2 ? L.rank[ig] : P.n;   // fin0
  }
  lds[tid] = v2; __syncthreads();
  for (int off = 1; off < 256; off <<= 1) {
    int t = (tid >= off) ? lds[tid-off] : 0; __syncthreads();
    lds[tid] += t; __syncthreads();
  }
  if (valid) L.misPre[ig] = lds[tid] - v2;
  if (tid == 0) L.btot[bid] = (unsigned)lds[255];
}
__global__ __launch_bounds__(BLOCK) void k_fin1(KParams P) {
  Lay L = mklay(P.ws, P.n, P.e);
  int v = blockIdx.x*BLOCK + threadIdx.x;
  if (v >= P.n) return;
  L.t1[v] = gmin_(L.colSrc, L.mm, L.colPtr[v], L.colPtr[v+1], L.mm[v]);
}
__global__ __launch_bounds__(BLOCK) void k_fin2(KParams P) {
  Lay L = mklay(P.ws, P.n, P.e);
  int v = blockIdx.x*BLOCK + threadIdx.x;
  if (v >= P.n) return;
  L.mr[v] = gmin_(L.colSrc, L.t1, L.colPtr[v], L.colPtr[v+1], L.t1[v]);
}
// misPre += prefix(btot); r2c; cnts[2]=num_mis  (scanB folded)
__global__ __launch_bounds__(BLOCK) void k_scanM3(KParams P) {
  Lay L = mklay(P.ws, P.n, P.e);
  int tid = threadIdx.x, bid = blockIdx.x;
  int base = btotPrefix(L.btot, bid);
  int total = btotPrefix(L.btot, SG);
  int chunk = (P.n + SG - 1)/SG;
  int ig = bid*chunk + tid;
  if (tid < chunk && ig < P.n) {
    int p = L.misPre[ig] + base;
    L.misPre[ig] = p;
    if (L.mis[ig]) L.r2c[L.rank[ig]] = p;
  }
  if (bid == 0 && tid == 0) L.cnts[2] = total;
}

__global__ __launch_bounds__(BLOCK) void k_clus(KParams P) {
  Lay L = mklay(P.ws, P.n, P.e);
  int gid = blockIdx.x*BLOCK + threadIdx.x;
  int M = L.cnts[2];
  long long M2 = (long long)M*M;
  for (int v = gid; v < P.n; v += NTHE) {
    int r3 = L.mr[v];
    L.clus[v] = (r3 >= 0 && r3 < P.n) ? L.r2c[r3] : 0;
  }
  bool pairOk = (M > 0) && (M2 < 0x7fffffffll) && (L.unionBase + M2 <= P.ws_ints);
  if (pairOk) {
    int m2i = (int)M2;
    for (int i = gid; i < m2i; i += NTHE) L.pairCnt[i] = 0;
  }
}

__global__ __launch_bounds__(BLOCK) void k_pair(KParams P) {
  Lay L = mklay(P.ws, P.n, P.e);
  int M = L.cnts[2];
  long long M2 = (long long)M*M;
  bool pairOk = (M > 0) && (M2 < 0x7fffffffll) && (L.unionBase + M2 <= P.ws_ints);
  if (!pairOk) return;
  const int* row = P.ei; const int* col = P.ei + P.e;
  int gid = blockIdx.x*BLOCK + threadIdx.x;
  for (int j = gid; j < P.e; j += NTHE) {
    int a = L.clus[row[j]], b2 = L.clus[col[j]];
    atomicAdd(&L.pairCnt[a*M + b2], 1);
  }
}

__global__ __launch_bounds__(BLOCK) void k_keep1(KParams P) {
  Lay L = mklay(P.ws, P.n, P.e);
  __shared__ int lds[256];
  int tid = threadIdx.x, bid = blockIdx.x;
  int M = L.cnts[2];
  long long M2 = (long long)M*M;
  bool pairOk = (M > 0) && (M2 < 0x7fffffffll) && (L.unionBase + M2 <= P.ws_ints);
  int m2i = pairOk ? (int)M2 : 0;
  int chunkP = pairOk ? (m2i + SG - 1)/SG : 0;
  int pstart = bid*chunkP; if (pstart > m2i) pstart = m2i;
  int pend = pstart + chunkP; if (pend > m2i) pend = m2i;
  int localKeep = 0;
  for (int i = pstart + tid; i < pend; i += BLOCK) {
    int c = L.pairCnt[i];
    if (c > 0 && (i / M) != (i % M)) ++localKeep;
  }
  lds[tid] = localKeep; __syncthreads();
  for (int off = 128; off > 0; off >>= 1) { if (tid < off) lds[tid] += lds[tid+off]; __syncthreads(); }
  if (tid == 0) L.btot[bid] = (unsigned)lds[0];
}

__global__ __launch_bounds__(BLOCK) void k_edges(KParams P) {
  Lay L = mklay(P.ws, P.n, P.e);
  __shared__ int lds[256];
  int tid = threadIdx.x, bid = blockIdx.x;
  int M = L.cnts[2];
  long long M2 = (long long)M*M;
  bool pairOk = (M > 0) && (M2 < 0x7fffffffll) && (L.unionBase + M2 <= P.ws_ints);
  if (!pairOk) return;
  int base = btotPrefix(L.btot, bid);
  int EK = btotPrefix(L.btot, SG);
  int m2i = (int)M2;
  int chunkP = (m2i + SG - 1)/SG;
  int pstart = bid*chunkP; if (pstart > m2i) pstart = m2i;
  int pend = pstart + chunkP; if (pend > m2i) pend = m2i;
  size_t eBase = (size_t)M * (size_t)P.d;
  bool outOk = (eBase + 3ull*(size_t)EK <= (size_t)P.out_size);
  int running2 = base;
  for (int t0 = pstart; t0 < pend; t0 += BLOCK) {
    int i = t0 + tid;
    int c = 0, kept = 0, a = 0, b2 = 0;
    if (i < pend) {
      c = L.pairCnt[i];
      a = i / M; b2 = i % M;
      kept = (c > 0 && a != b2) ? 1 : 0;
    }
    lds[tid] = kept; __syncthreads();
    for (int off = 1; off < 256; off <<= 1) {
      int t = (tid >= off) ? lds[tid-off] : 0; __syncthreads();
      lds[tid] += t; __syncthreads();
    }
    int incl = lds[tid], tot = lds[255];
    if (kept && outOk) {
      int j2 = running2 + incl - 1;
      P.out[eBase + (size_t)j2] = (float)a;
      P.out[eBase + (size_t)EK + (size_t)j2] = (float)b2;
      P.out[eBase + 2ull*(size_t)EK + (size_t)j2] = (float)c;
    }
    running2 += tot;
    __syncthreads();
  }
}

__global__ __launch_bounds__(BLOCK) void k_xpool(KParams P) {
  Lay L = mklay(P.ws, P.n, P.e);
  int gid = blockIdx.x*BLOCK + threadIdx.x;
  int lane = gid & 63, gwv = gid >> 6;
  int M = L.cnts[2];
  int d4 = P.d >> 2;
  size_t eBase = (size_t)M * (size_t)P.d;
  if (eBase > (size_t)P.out_size) return;
  for (int v = gwv; v < P.n; v += NWVE) {
    if (L.mis[v]) {
      int p = L.misPre[v];
      float sc = L.score[v];
      const float4* xr = (const float4*)(P.x + (size_t)v*P.d);
      float4* outr = (float4*)P.out + (size_t)p*d4;
      for (int q = lane; q < d4; q += 64) {
        float4 xv = xr[q];
        outr[q] = make_float4(xv.x*sc, xv.y*sc, xv.z*sc, xv.w*sc);
      }
    }
  }
}

extern "C" void kernel_launch(void* const* d_in, const int* in_sizes, int n_in,
                              void* d_out, int out_size, void* d_ws, size_t ws_size,
                              hipStream_t stream) {
  KParams P;
  P.x  = (const float*)d_in[0];
  P.ei = (const int*)d_in[1];
  P.w  = (const float*)d_in[2];
  P.bb = (const float*)d_in[3];
  P.out = (float*)d_out;
  P.d = in_sizes[2];            // 256
  P.n = in_sizes[0] / P.d;      // 100000
  P.e = in_sizes[1] / 2;        // 1600000
  P.out_size = out_size;
  P.ws = (int*)d_ws;
  P.ws_ints = (long long)(ws_size / 4);
  const int nblk = (P.n + BLOCK - 1) / BLOCK;

  k_score <<<EGRID, BLOCK, 0, stream>>>(P);
  k_degree<<<EGRID, BLOCK, 0, stream>>>(P);
  k_scan1 <<<SG,    BLOCK, 0, stream>>>(P);
  k_scan3 <<<SG,    BLOCK, 0, stream>>>(P);
  k_csr   <<<EGRID, BLOCK, 0, stream>>>(P);
  k_keygen<<<nblk,  BLOCK, 0, stream>>>(P);
  for (int pass = 0; pass < 4; ++pass) {
    k_sort_local  <<<SG, BLOCK, 0, stream>>>(P, pass);
    k_sort_scan1  <<<64, BLOCK, 0, stream>>>(P);
    k_sort_scatter<<<SG, BLOCK, 0, stream>>>(P, pass);
  }
  k_rankinit<<<nblk, BLOCK, 0, stream>>>(P);
  for (int t = 0; t < DENSE_ITERS; ++t) {
    k_dmin <<<nblk, BLOCK, 0, stream>>>(P, t);
    k_dsel <<<nblk, BLOCK, 0, stream>>>(P, t);
    k_dor  <<<nblk, BLOCK, 0, stream>>>(P, t);
    k_drb  <<<nblk, BLOCK, 0, stream>>>(P, t);
  }
  k_tcomp1 <<<SG,   BLOCK, 0, stream>>>(P);
  k_tcomp3 <<<SG,   BLOCK, 0, stream>>>(P);
  k_tbuild <<<nblk, BLOCK, 0, stream>>>(P);
  k_trounds<<<1,    1024,  0, stream>>>(P);
  k_scanM1<<<SG, BLOCK, 0, stream>>>(P);
  k_fin1  <<<nblk, BLOCK, 0, stream>>>(P);
  k_fin2  <<<nblk, BLOCK, 0, stream>>>(P);
  k_scanM3<<<SG, BLOCK, 0, stream>>>(P);
  k_clus <<<EGRID, BLOCK, 0, stream>>>(P);
  k_pair <<<EGRID, BLOCK, 0, stream>>>(P);
  k_keep1<<<SG,    BLOCK, 0, stream>>>(P);
  k_edges<<<SG,    BLOCK, 0, stream>>>(P);
  k_xpool<<<EGRID, BLOCK, 0, stream>>>(P);
}

// Round 4
// 815.460 us; speedup vs baseline: 1.2540x; 1.0587x over previous
//
#include <hip/hip_runtime.h>
#include <math.h>

#define BLOCK 256
#define EGRID 2048                 // edge-parallel / bulk kernels
#define SG    512                  // scan/sort kernels (fixed structure)
#define NTHE (EGRID*BLOCK)
#define NWVE (NTHE/64)
#define INF_ 0x7fffffff
#define TB   6000                  // bitset-tail threshold (capacity ~7155)
#define AWMAX 224
#define TBCAP 7168                 // AWMAX*32
#define DENSE_ITERS 6

struct KParams {
  const float* x;
  const int*   ei;
  const float* w;
  const float* bb;
  float* out;
  int n, e, d, out_size;
  int* ws;
  long long ws_ints;
};

struct Lay {
  float* score; int *ks1,*cursor;
  int *keyA,*idxA,*keyB,*idxB,*lrank;
  int *rank,*mr,*t1,*mis,*mm,*misPre,*r2c,*clus,*colPtr,*rowPtr;
  unsigned *bh,*dtot,*dbase,*btot,*bbase;
  int *cnts,*colSrc,*rowDst,*pairCnt;
  long long unionBase;
};

__device__ __host__ inline Lay mklay(int* ws, int n, int e) {
  Lay L;
  L.score=(float*)ws;
  L.ks1   = ws + (size_t)1*n;
  L.cursor= ws + (size_t)2*n;          // CSR cursor -> nodeIdx (tail)
  L.keyA  = ws + (size_t)3*n;          // sort key -> active list parity 0
  L.idxA  = ws + (size_t)4*n;          // sort payload: idxA[i]=node with rank i
  L.keyB  = ws + (size_t)5*n;          // sort key -> active list parity 1
  L.idxB  = ws + (size_t)6*n;
  L.lrank = ws + (size_t)7*n;          // sort tmp -> tail sorted list S
  L.rank  = ws + (size_t)8*n;
  L.mr    = ws + (size_t)9*n;          // tmin temp; final khop result
  L.t1    = ws + (size_t)10*n;         // tor temp; tcomp prefix; fin temp
  L.mis   = ws + (size_t)11*n;
  L.mm    = ws + (size_t)12*n;         // a[] = active?rank:INF; then fin0 output
  L.misPre= ws + (size_t)13*n;         // post misPre
  L.r2c   = ws + (size_t)14*n;
  L.clus  = ws + (size_t)15*n;
  L.colPtr= ws + (size_t)16*n;         // n+1
  L.rowPtr= ws + (size_t)17*n + 64;    // unused (layout keep)
  int* sm = ws + (size_t)18*n + 128;
  L.bh    = (unsigned*)sm;             // 256*SG
  L.dtot  = L.bh + 256*SG;             // 256
  L.dbase = L.dtot + 256;              // 256 (unused now)
  L.btot  = L.dbase + 256;             // SG
  L.bbase = L.btot + SG;               // SG (unused now)
  L.cnts  = (int*)(L.bbase + SG);      // 16
  L.unionBase = 18ll*n + 128 + 256ll*SG + 512 + 2ll*SG + 16;
  L.colSrc  = ws + L.unionBase;        // e ints (in-CSR)
  L.rowDst  = L.colSrc + e;            // e ints -> tail bitset rows (bs)
  L.pairCnt = ws + L.unionBase;        // M*M ints (aliased, post-loop)
  return L;
}

// ---- unrolled gather reducers ----
__device__ inline int gmin_(const int* __restrict__ s, const int* __restrict__ val,
                            int p, int pe, int m) {
  for (; p+3 < pe; p += 4) {
    int a0=s[p],a1=s[p+1],a2=s[p+2],a3=s[p+3];
    int t0=val[a0],t1=val[a1],t2=val[a2],t3=val[a3];
    t0=min(t0,t1); t2=min(t2,t3); t0=min(t0,t2); if (t0<m) m=t0;
  }
  for (; p<pe; ++p){ int t=val[s[p]]; if (t<m) m=t; }
  return m;
}
__device__ inline int gor_(const int* __restrict__ s, const int* __restrict__ val,
                           int p, int pe, int m) {
  for (; p+3 < pe; p += 4) m |= val[s[p]] | val[s[p+1]] | val[s[p+2]] | val[s[p+3]];
  for (; p<pe; ++p) m |= val[s[p]];
  return m;
}
__device__ inline int gsum_(const int* __restrict__ s, const int* __restrict__ val,
                            int p, int pe, int m) {
  for (; p+3 < pe; p += 4) m += val[s[p]] + val[s[p+1]] + val[s[p+2]] + val[s[p+3]];
  for (; p<pe; ++p) m += val[s[p]];
  return m;
}

// sum of btot[0..upto) within a 256-thread block (barrier-protected shared reuse)
__device__ inline int btotPrefix(const unsigned* btot, int upto) {
  __shared__ int red[256];
  int tid = threadIdx.x;
  int partial = 0;
  for (int idx = tid; idx < upto; idx += 256) partial += (int)btot[idx];
  __syncthreads();
  red[tid] = partial; __syncthreads();
  for (int off = 128; off > 0; off >>= 1) { if (tid < off) red[tid] += red[tid+off]; __syncthreads(); }
  int r = red[0]; __syncthreads();
  return r;
}

// ---------------- phase kernels ----------------
__global__ __launch_bounds__(BLOCK) void k_score(KParams P) {
  Lay L = mklay(P.ws, P.n, P.e);
  int gid = blockIdx.x*BLOCK + threadIdx.x;
  int lane = gid & 63, gwv = gid >> 6;
  int d4 = P.d >> 2;
  double bconst = (double)P.bb[0];
  const float4* w4 = (const float4*)P.w;
  for (int v = gwv; v < P.n; v += NWVE) {
    const float4* xr = (const float4*)(P.x + (size_t)v*P.d);
    double s = 0.0;
    for (int q = lane; q < d4; q += 64) {
      float4 xv = xr[q], wv = w4[q];
      s += (double)xv.x*wv.x + (double)xv.y*wv.y + (double)xv.z*wv.z + (double)xv.w*wv.w;
    }
    for (int off = 32; off > 0; off >>= 1) s += __shfl_down(s, off);
    if (lane == 0) L.score[v] = (float)(1.0/(1.0+exp(-(s+bconst))));
  }
  for (int v = gid; v < P.n; v += NTHE) L.ks1[v] = 0;
}

__global__ __launch_bounds__(BLOCK) void k_degree(KParams P) {
  Lay L = mklay(P.ws, P.n, P.e);
  const int* col = P.ei + P.e;
  int gid = blockIdx.x*BLOCK + threadIdx.x;
  for (int j = gid; j < P.e; j += NTHE) atomicAdd(&L.ks1[col[j]], 1);
}

__global__ __launch_bounds__(BLOCK) void k_scan1(KParams P) {
  Lay L = mklay(P.ws, P.n, P.e);
  __shared__ int lds[256];
  int tid = threadIdx.x, bid = blockIdx.x;
  int chunk = (P.n + SG - 1)/SG;
  int ig = bid*chunk + tid;
  bool valid = (tid < chunk) && (ig < P.n);
  int v2 = valid ? L.ks1[ig] : 0;
  lds[tid] = v2; __syncthreads();
  for (int off = 1; off < 256; off <<= 1) {
    int t = (tid >= off) ? lds[tid-off] : 0; __syncthreads();
    lds[tid] += t; __syncthreads();
  }
  if (valid) L.colPtr[ig] = lds[tid] - v2;
  if (tid == 0) L.btot[bid] = (unsigned)lds[255];
}

// colPtr += prefix(btot); cursor=colPtr; ks1+=1  (btot scan folded in)
__global__ __launch_bounds__(BLOCK) void k_scan3(KParams P) {
  Lay L = mklay(P.ws, P.n, P.e);
  int tid = threadIdx.x, bid = blockIdx.x;
  int base = btotPrefix(L.btot, bid);
  int chunk = (P.n + SG - 1)/SG;
  int ig = bid*chunk + tid;
  if (tid < chunk && ig < P.n) {
    int cp = L.colPtr[ig] + base;
    L.colPtr[ig] = cp; L.cursor[ig] = cp; L.ks1[ig] += 1;
  }
  if (bid == 0 && tid == 0) L.colPtr[P.n] = P.e;
}

// XCD-partitioned CSR fill: group g = blockIdx&7 (round-robin block->XCD
// dispatch) commits only cols in its 1/8 range. Each group's scatter region
// (~e/8 ints of colSrc) is contiguous and L2-resident on its XCD -> lines are
// fully filled before one clean write-back (kills the 16x write amplification
// of the global random scatter). Edge re-reads are served by the die-level L3.
__global__ __launch_bounds__(BLOCK) void k_csr(KParams P) {
  Lay L = mklay(P.ws, P.n, P.e);
  const int* __restrict__ row = P.ei; const int* __restrict__ col = P.ei + P.e;
  int grp = blockIdx.x & 7;
  int bwg = blockIdx.x >> 3;
  int nbw = gridDim.x >> 3;
  int lo = (int)((long long)grp * P.n >> 3);
  int hi = (int)((long long)(grp+1) * P.n >> 3);
  int gid = bwg*BLOCK + threadIdx.x;
  int stride = nbw*BLOCK;
  for (int j = gid; j < P.e; j += stride) {
    int c = col[j];
    if (c >= lo && c < hi) {
      int pos = atomicAdd(&L.cursor[c], 1);
      L.colSrc[pos] = row[j];
    }
  }
}

__global__ __launch_bounds__(BLOCK) void k_keygen(KParams P) {
  Lay L = mklay(P.ws, P.n, P.e);
  int v = blockIdx.x*BLOCK + threadIdx.x;
  if (v >= P.n) return;
  int s = gsum_(L.colSrc, L.ks1, L.colPtr[v], L.colPtr[v+1], L.ks1[v]);
  float upd = L.score[v] / (float)s;
  unsigned u = __float_as_uint(upd);
  u = (u & 0x80000000u) ? (~u) : (u | 0x80000000u);
  ((unsigned*)L.keyA)[v] = ~u;
  ((unsigned*)L.idxA)[v] = (unsigned)v;
}

__global__ __launch_bounds__(BLOCK) void k_sort_local(KParams P, int pass) {
  Lay L = mklay(P.ws, P.n, P.e);
  __shared__ int ldsH[1024];
  int tid = threadIdx.x, bid = blockIdx.x, lane = tid & 63, wib = tid >> 6;
  unsigned* sk = (pass & 1) ? (unsigned*)L.keyB : (unsigned*)L.keyA;
  int shift = pass*8;
  for (int i = tid; i < 1024; i += BLOCK) ldsH[i] = 0;
  __syncthreads();
  int chunk = (P.n + SG - 1)/SG;
  int ig = bid*chunk + tid;
  bool valid = (tid < chunk) && (ig < P.n);
  int dig = 0;
  if (valid) dig = (int)((sk[ig] >> shift) & 255u);
  unsigned long long mmask = __ballot(valid);
  for (int b = 0; b < 8; ++b) {
    unsigned long long bm = __ballot((dig >> b) & 1);
    mmask &= ((dig >> b) & 1) ? bm : ~bm;
  }
  int lp = 0;
  if (valid) {
    lp = __popcll(mmask & ((1ull << lane) - 1ull));
    if (lp == 0) ldsH[wib*256 + dig] = __popcll(mmask);
  }
  __syncthreads();
  if (tid < 256) {
    int c0=ldsH[tid], c1=ldsH[256+tid], c2=ldsH[512+tid], c3=ldsH[768+tid];
    ldsH[tid]=0; ldsH[256+tid]=c0; ldsH[512+tid]=c0+c1; ldsH[768+tid]=c0+c1+c2;
    L.bh[(size_t)tid*SG + bid] = (unsigned)(c0+c1+c2+c3);
  }
  __syncthreads();
  if (valid) ((unsigned*)L.lrank)[ig] = (unsigned)(ldsH[wib*256 + dig] + lp);
}

__global__ __launch_bounds__(BLOCK) void k_sort_scan1(KParams P) {
  Lay L = mklay(P.ws, P.n, P.e);
  int g = blockIdx.x*BLOCK + threadIdx.x;
  int dg = g >> 6, lane = g & 63;
  if (dg >= 256) return;
  unsigned running = 0;
  for (int r = 0; r < SG/64; ++r) {
    unsigned v = L.bh[(size_t)dg*SG + r*64 + lane];
    unsigned incl = v;
    for (int off = 1; off < 64; off <<= 1) { unsigned t = __shfl_up(incl, off); if (lane >= off) incl += t; }
    L.bh[(size_t)dg*SG + r*64 + lane] = incl - v + running;
    running += __shfl(incl, 63);
  }
  if (lane == 0) L.dtot[dg] = running;
}

// scatter with in-block dbase recompute (scanD folded in)
__global__ __launch_bounds__(BLOCK) void k_sort_scatter(KParams P, int pass) {
  Lay L = mklay(P.ws, P.n, P.e);
  __shared__ unsigned sdb[256];
  unsigned *sk,*si,*dk,*di;
  if (pass & 1) { sk=(unsigned*)L.keyB; si=(unsigned*)L.idxB; dk=(unsigned*)L.keyA; di=(unsigned*)L.idxA; }
  else          { sk=(unsigned*)L.keyA; si=(unsigned*)L.idxA; dk=(unsigned*)L.keyB; di=(unsigned*)L.idxB; }
  int tid = threadIdx.x, bid = blockIdx.x;
  unsigned myv = L.dtot[tid];
  sdb[tid] = myv; __syncthreads();
  for (int off = 1; off < 256; off <<= 1) {
    unsigned t = (tid >= off) ? sdb[tid-off] : 0u; __syncthreads();
    sdb[tid] += t; __syncthreads();
  }
  unsigned excl = sdb[tid] - myv; __syncthreads();
  sdb[tid] = excl; __syncthreads();
  int chunk = (P.n + SG - 1)/SG;
  int ig = bid*chunk + tid;
  if (tid < chunk && ig < P.n) {
    unsigned key = sk[ig];
    int dig = (int)((key >> (pass*8)) & 255u);
    unsigned pos = sdb[dig] + L.bh[(size_t)dig*SG + bid] + ((unsigned*)L.lrank)[ig];
    dk[pos] = key; di[pos] = si[ig];
  }
}

__global__ __launch_bounds__(BLOCK) void k_rankinit(KParams P) {
  Lay L = mklay(P.ws, P.n, P.e);
  int i = blockIdx.x*BLOCK + threadIdx.x;
  if (blockIdx.x == 0 && threadIdx.x == 0) {
    L.cnts[4] = P.n;   // A for parity 0
    L.cnts[5] = 0;
  }
  if (i >= P.n) return;
  int v = (int)((unsigned*)L.idxA)[i];
  L.rank[v] = i;
  L.mm[v] = i;        // a[] = rank (all active)
  L.mis[v] = 0;
}

// ---- dense KMIS iterations (static parity = t&1) ----
__global__ __launch_bounds__(BLOCK) void k_dmin(KParams P, int t) {
  Lay L = mklay(P.ws, P.n, P.e);
  if (L.cnts[4+(t&1)] <= TB) return;
  int w = blockIdx.x*BLOCK + threadIdx.x;
  if (w >= P.n) return;
  L.mr[w] = gmin_(L.colSrc, L.mm, L.colPtr[w], L.colPtr[w+1], L.mm[w]);
}
__global__ __launch_bounds__(BLOCK) void k_dsel(KParams P, int t) {
  Lay L = mklay(P.ws, P.n, P.e);
  int q = t & 1;
  int A = L.cnts[4+q];
  if (A <= TB) return;
  int i = blockIdx.x*BLOCK + threadIdx.x;
  if (i >= A) return;
  int v = (t == 0) ? i : (q ? L.keyB : L.keyA)[i];
  int m2 = gmin_(L.colSrc, L.mr, L.colPtr[v], L.colPtr[v+1], L.mr[v]);
  if (L.rank[v] == m2) L.mis[v] = 1;
}
__global__ __launch_bounds__(BLOCK) void k_dor(KParams P, int t) {
  Lay L = mklay(P.ws, P.n, P.e);
  int q = t & 1;
  if (L.cnts[4+q] <= TB) return;
  int w = blockIdx.x*BLOCK + threadIdx.x;
  if (blockIdx.x == 0 && threadIdx.x == 0) L.cnts[4+(1-q)] = 0;
  if (w >= P.n) return;
  L.t1[w] = gor_(L.colSrc, L.mis, L.colPtr[w], L.colPtr[w+1], L.mis[w]);
}
__global__ __launch_bounds__(BLOCK) void k_drb(KParams P, int t) {
  Lay L = mklay(P.ws, P.n, P.e);
  int q = t & 1;
  int A = L.cnts[4+q];
  int* act  = (t == 0) ? (int*)0 : (q ? L.keyB : L.keyA);
  int* nact = q ? L.keyA : L.keyB;
  int gid = blockIdx.x*BLOCK + threadIdx.x;
  if (A <= TB) {                       // copy mode: keep parity flipping static
    for (int i = gid; i < A; i += (P.n + BLOCK - 1)/BLOCK*BLOCK) nact[i] = act[i];
    if (gid == 0) L.cnts[4+(1-q)] = A;
    return;
  }
  int lane = threadIdx.x & 63;
  bool aliveF = false; int v = 0;
  if (gid < A) {
    v = (t == 0) ? gid : act[gid];
    int dead = gor_(L.colSrc, L.t1, L.colPtr[v], L.colPtr[v+1], L.t1[v]);
    if (dead) L.mm[v] = INF_; else aliveF = true;
  }
  unsigned long long mk = __ballot(aliveF);
  int cntw = __popcll(mk);
  if (cntw) {
    int fl = __ffsll((unsigned long long)mk) - 1;
    int base = 0;
    if (lane == fl) base = atomicAdd(&L.cnts[4+(1-q)], cntw);
    base = __shfl(base, fl);
    if (aliveF) nact[base + __popcll(mk & ((1ull<<lane)-1ull))] = v;
  }
}

// ---- tail: compact survivors in rank order (flags via mm != INF over idxA) ----
__global__ __launch_bounds__(BLOCK) void k_tcomp1(KParams P) {
  Lay L = mklay(P.ws, P.n, P.e);
  __shared__ int lds[256];
  int tid = threadIdx.x, bid = blockIdx.x;
  int chunk = (P.n + SG - 1)/SG;
  int ig = bid*chunk + tid;
  bool valid = (tid < chunk) && (ig < P.n);
  int f = 0;
  if (valid) { int v = (int)((unsigned*)L.idxA)[ig]; f = (L.mm[v] != INF_) ? 1 : 0; }
  lds[tid] = f; __syncthreads();
  for (int off = 1; off < 256; off <<= 1) {
    int t = (tid >= off) ? lds[tid-off] : 0; __syncthreads();
    lds[tid] += t; __syncthreads();
  }
  if (valid) L.t1[ig] = lds[tid] - f;
  if (tid == 0) L.btot[bid] = (unsigned)lds[255];
}
// S[pos]=v ordered by rank; cursor[v]=pos or -1; zero bs (+trans if it fits)
__global__ __launch_bounds__(BLOCK) void k_tcomp3(KParams P) {
  Lay L = mklay(P.ws, P.n, P.e);
  int tid = threadIdx.x, bid = blockIdx.x;
  int base = btotPrefix(L.btot, bid);
  int chunk = (P.n + SG - 1)/SG;
  int ig = bid*chunk + tid;
  if (tid < chunk && ig < P.n) {
    int v = (int)((unsigned*)L.idxA)[ig];
    if (L.mm[v] != INF_) {
      int pos = L.t1[ig] + base;
      L.lrank[pos] = v;          // S
      L.cursor[v] = pos;         // nodeIdx
    } else L.cursor[v] = -1;
  }
  int A = L.cnts[4];
  if (A > 0) {
    int AW = (A + 31) >> 5;
    int AWP = (AW + 3) & ~3;     // 16B-padded row stride
    unsigned* bs = (unsigned*)L.rowDst;
    long long tot = (long long)A * AWP;
    for (long long idx = (long long)bid*BLOCK + tid; idx < tot; idx += (long long)SG*BLOCK) bs[idx] = 0u;
    bool transOk = (L.unionBase + 2ll*P.e + tot <= P.ws_ints);
    if (transOk) {
      unsigned* tr = (unsigned*)(P.ws + L.unionBase + 2ll*P.e);
      for (long long idx = (long long)bid*BLOCK + tid; idx < tot; idx += (long long)SG*BLOCK) tr[idx] = 0u;
    }
  }
}
// build in2closed source bitsets (+transpose), wave per row
__global__ __launch_bounds__(BLOCK) void k_tbuild(KParams P) {
  Lay L = mklay(P.ws, P.n, P.e);
  int A = L.cnts[4];
  if (A <= 0) return;
  int AW = (A + 31) >> 5;
  int AWP = (AW + 3) & ~3;
  unsigned* bs = (unsigned*)L.rowDst;
  bool transOk = (L.unionBase + 2ll*P.e + (long long)A*AWP <= P.ws_ints);
  unsigned* tr = transOk ? (unsigned*)(P.ws + L.unionBase + 2ll*P.e) : (unsigned*)0;
  const int* __restrict__ cp = L.colPtr;
  const int* __restrict__ cs = L.colSrc;
  const int* __restrict__ nodeIdx = L.cursor;
  int gid = blockIdx.x*BLOCK + threadIdx.x;
  int lane = gid & 63, gwv = gid >> 6;
  int nW = (gridDim.x*BLOCK) >> 6;
  for (int i = gwv; i < A; i += nW) {
    int v = L.lrank[i];
    unsigned* row = bs + (size_t)i*AWP;
    unsigned ibit = 1u << (i & 31);
    int iw = i >> 5;
    if (lane == 0) {
      atomicOr(&row[iw], ibit);
      if (tr) atomicOr(&tr[(size_t)i*AWP + iw], ibit);
    }
    int p0 = cp[v], p1 = cp[v+1];
    for (int p = p0 + lane; p < p1; p += 64) {
      int u = cs[p];
      int j = nodeIdx[u];
      if (j >= 0) {
        atomicOr(&row[j >> 5], 1u << (j & 31));
        if (tr) atomicOr(&tr[(size_t)j*AWP + iw], ibit);
      }
      int p3 = cp[u+1];
      for (int p2 = cp[u]; p2 < p3; ++p2) {
        int w2 = cs[p2];
        int j2 = nodeIdx[w2];
        if (j2 >= 0) {
          atomicOr(&row[j2 >> 5], 1u << (j2 & 31));
          if (tr) atomicOr(&tr[(size_t)j2*AWP + iw], ibit);
        }
      }
    }
  }
}
// all MIS rounds in one 1024-thread block.
// ph1: pipelined 2x-uint4 granule scan (R0 structure) + GRANULE-level witness
// cache: pw[i] = first granule whose row&alive may be nonzero; granules below
// it are permanently zero (alive only shrinks), so each round resumes there.
// ph2: dead = union of trans rows of selected (exact rewrite of the kill rule);
// falls back to breakless full row scans if the transpose didn't fit.
__global__ __launch_bounds__(1024) void k_trounds(KParams P) {
  Lay L = mklay(P.ws, P.n, P.e);
  __shared__ __align__(16) unsigned aliveW[AWMAX];
  __shared__ __align__(16) unsigned selW[AWMAX];
  __shared__ __align__(16) unsigned deadW[AWMAX];
  __shared__ int selList[TBCAP];
  __shared__ unsigned char pw[TBCAP];
  __shared__ int scnt, selCnt;
  int A = L.cnts[4];
  if (A <= 0) return;
  int AW = (A + 31) >> 5;
  int AWP = (AW + 3) & ~3;
  const unsigned* __restrict__ bs = (const unsigned*)L.rowDst;
  bool transOk = (L.unionBase + 2ll*P.e + (long long)A*AWP <= P.ws_ints);
  const unsigned* __restrict__ tr = (const unsigned*)(P.ws + L.unionBase + 2ll*P.e);
  const int* __restrict__ S = L.lrank;
  const uint4* __restrict__ a4 = (const uint4*)aliveW;
  int tid = threadIdx.x;
  for (int w = tid; w < AWP; w += 1024) {
    int base = w*32; int c = A - base;
    aliveW[w] = (c >= 32) ? 0xffffffffu : ((c > 0) ? ((1u << c) - 1u) : 0u);
  }
  for (int i = tid; i < A; i += 1024) pw[i] = 0;
  __syncthreads();
  for (int rounds = 0; rounds < 8192; ++rounds) {
    for (int w = tid; w < AWP; w += 1024) { selW[w] = 0u; deadW[w] = 0u; }
    if (tid == 0) { scnt = 0; selCnt = 0; }
    __syncthreads();
    // ph1: select alive i with no alive smaller-ranked in-2 source
    for (int i = tid; i < A; i += 1024) {
      if ((aliveW[i>>5] >> (i&31)) & 1u) {
        const unsigned* __restrict__ row = bs + (size_t)i*AWP;
        const uint4* __restrict__ r4 = (const uint4*)row;
        int wl = i >> 5;
        int nf = wl >> 2;                 // full granules strictly below word wl
        int g = (int)pw[i];
        unsigned any = 0;
        for (; g + 2 <= nf; g += 2) {     // 2x uint4 in flight, granule-level resolve
          uint4 a = r4[g],   b = r4[g+1];
          uint4 av = a4[g],  bv = a4[g+1];
          unsigned r0 = (a.x&av.x)|(a.y&av.y)|(a.z&av.z)|(a.w&av.w);
          unsigned r1 = (b.x&bv.x)|(b.y&bv.y)|(b.z&bv.z)|(b.w&bv.w);
          if (r0 | r1) { any = 1; if (!r0) ++g; break; }   // advance past verified-zero granule
        }
        if (!any && g < nf) {
          uint4 a = r4[g]; uint4 av = a4[g];
          unsigned r0 = (a.x&av.x)|(a.y&av.y)|(a.z&av.z)|(a.w&av.w);
          if (r0) any = 1; else ++g;
        }
        pw[i] = (unsigned char)g;         // granules < g are permanently dead
        if (!any) {
          for (int w2 = nf << 2; w2 < wl; ++w2) any |= row[w2] & aliveW[w2];
          if (!any && (i & 31)) any = row[wl] & aliveW[wl] & ((1u << (i&31)) - 1u);
        }
        if (!any) {
          int sp = atomicAdd(&selCnt, 1);
          selList[sp] = i;
          atomicOr(&selW[i>>5], 1u << (i&31));
          L.mis[S[i]] = 1;
        }
      }
    }
    __syncthreads();
    int nsel = selCnt;
    if (nsel == 0) break;            // alive empty (defensive; min-alive is always selectable)
    int surv = 0;
    if (transOk) {
      // accumulate dead = OR of trans rows of selected; coalesced (w = word, 4 q-slices)
      int w = tid & 255, qs = tid >> 8;
      if (w < AW) {
        unsigned acc = 0;
        for (int q = qs; q < nsel; q += 4) acc |= tr[(size_t)selList[q]*AWP + w];
        if (acc) atomicOr(&deadW[w], acc);
      }
      __syncthreads();
      for (int w2 = tid; w2 < AW; w2 += 1024) {
        unsigned na = aliveW[w2] & ~deadW[w2];
        aliveW[w2] = na;
        surv += __popc(na);
      }
    } else {
      for (int i = tid; i < A; i += 1024) {
        if ((aliveW[i>>5] >> (i&31)) & 1u) {
          const uint4* __restrict__ r4 = (const uint4*)(bs + (size_t)i*AWP);
          const uint4* __restrict__ s4 = (const uint4*)selW;
          unsigned dead = 0;
          int ng = AWP >> 2;
          for (int g2 = 0; g2 < ng; ++g2) {
            uint4 a = r4[g2], sa = s4[g2];
            dead |= (a.x&sa.x)|(a.y&sa.y)|(a.z&sa.z)|(a.w&sa.w);
          }
          if (dead) atomicAnd(&aliveW[i>>5], ~(1u << (i&31)));
          else ++surv;
        }
      }
    }
    if (surv) atomicAdd(&scnt, surv);
    __syncthreads();
    int sc = scnt;
    __syncthreads();
    if (sc == 0) break;
  }
}

// ---- final khop_min; fin0 folded into scanM1 ----
__global__ __launch_bounds__(BLOCK) void k_scanM1(KParams P) {
  Lay L = mklay(P.ws, P.n, P.e);
  __shared__ int lds[256];
  int tid = threadIdx.x, bid = blockIdx.x;
  int chunk = (P.n + SG - 1)/SG;
  int ig = bid*chunk + tid;
  bool valid = (tid < chunk) && (ig < P.n);
  int v2 = 0;
  if (valid) {
    v2 = L.mis[ig];
    L.mm[ig] = v2 ? L.rank[ig] : P.n;   // fin0
  }
  lds[tid] = v2; __syncthreads();
  for (int off = 1; off < 256; off <<= 1) {
    int t = (tid >= off) ? lds[tid-off] : 0; __syncthreads();
    lds[tid] += t; __syncthreads();
  }
  if (valid) L.misPre[ig] = lds[tid] - v2;
  if (tid == 0) L.btot[bid] = (unsigned)lds[255];
}
__global__ __launch_bounds__(BLOCK) void k_fin1(KParams P) {
  Lay L = mklay(P.ws, P.n, P.e);
  int v = blockIdx.x*BLOCK + threadIdx.x;
  if (v >= P.n) return;
  L.t1[v] = gmin_(L.colSrc, L.mm, L.colPtr[v], L.colPtr[v+1], L.mm[v]);
}
__global__ __launch_bounds__(BLOCK) void k_fin2(KParams P) {
  Lay L = mklay(P.ws, P.n, P.e);
  int v = blockIdx.x*BLOCK + threadIdx.x;
  if (v >= P.n) return;
  L.mr[v] = gmin_(L.colSrc, L.t1, L.colPtr[v], L.colPtr[v+1], L.t1[v]);
}
// misPre += prefix(btot); r2c; cnts[2]=num_mis  (scanB folded)
__global__ __launch_bounds__(BLOCK) void k_scanM3(KParams P) {
  Lay L = mklay(P.ws, P.n, P.e);
  int tid = threadIdx.x, bid = blockIdx.x;
  int base = btotPrefix(L.btot, bid);
  int total = btotPrefix(L.btot, SG);
  int chunk = (P.n + SG - 1)/SG;
  int ig = bid*chunk + tid;
  if (tid < chunk && ig < P.n) {
    int p = L.misPre[ig] + base;
    L.misPre[ig] = p;
    if (L.mis[ig]) L.r2c[L.rank[ig]] = p;
  }
  if (bid == 0 && tid == 0) L.cnts[2] = total;
}

__global__ __launch_bounds__(BLOCK) void k_clus(KParams P) {
  Lay L = mklay(P.ws, P.n, P.e);
  int gid = blockIdx.x*BLOCK + threadIdx.x;
  int M = L.cnts[2];
  long long M2 = (long long)M*M;
  for (int v = gid; v < P.n; v += NTHE) {
    int r3 = L.mr[v];
    L.clus[v] = (r3 >= 0 && r3 < P.n) ? L.r2c[r3] : 0;
  }
  bool pairOk = (M > 0) && (M2 < 0x7fffffffll) && (L.unionBase + M2 <= P.ws_ints);
  if (pairOk) {
    int m2i = (int)M2;
    for (int i = gid; i < m2i; i += NTHE) L.pairCnt[i] = 0;
  }
}

__global__ __launch_bounds__(BLOCK) void k_pair(KParams P) {
  Lay L = mklay(P.ws, P.n, P.e);
  int M = L.cnts[2];
  long long M2 = (long long)M*M;
  bool pairOk = (M > 0) && (M2 < 0x7fffffffll) && (L.unionBase + M2 <= P.ws_ints);
  if (!pairOk) return;
  const int* row = P.ei; const int* col = P.ei + P.e;
  int gid = blockIdx.x*BLOCK + threadIdx.x;
  for (int j = gid; j < P.e; j += NTHE) {
    int a = L.clus[row[j]], b2 = L.clus[col[j]];
    atomicAdd(&L.pairCnt[a*M + b2], 1);
  }
}

__global__ __launch_bounds__(BLOCK) void k_keep1(KParams P) {
  Lay L = mklay(P.ws, P.n, P.e);
  __shared__ int lds[256];
  int tid = threadIdx.x, bid = blockIdx.x;
  int M = L.cnts[2];
  long long M2 = (long long)M*M;
  bool pairOk = (M > 0) && (M2 < 0x7fffffffll) && (L.unionBase + M2 <= P.ws_ints);
  int m2i = pairOk ? (int)M2 : 0;
  int chunkP = pairOk ? (m2i + SG - 1)/SG : 0;
  int pstart = bid*chunkP; if (pstart > m2i) pstart = m2i;
  int pend = pstart + chunkP; if (pend > m2i) pend = m2i;
  int localKeep = 0;
  for (int i = pstart + tid; i < pend; i += BLOCK) {
    int c = L.pairCnt[i];
    if (c > 0 && (i / M) != (i % M)) ++localKeep;
  }
  lds[tid] = localKeep; __syncthreads();
  for (int off = 128; off > 0; off >>= 1) { if (tid < off) lds[tid] += lds[tid+off]; __syncthreads(); }
  if (tid == 0) L.btot[bid] = (unsigned)lds[0];
}

__global__ __launch_bounds__(BLOCK) void k_edges(KParams P) {
  Lay L = mklay(P.ws, P.n, P.e);
  __shared__ int lds[256];
  int tid = threadIdx.x, bid = blockIdx.x;
  int M = L.cnts[2];
  long long M2 = (long long)M*M;
  bool pairOk = (M > 0) && (M2 < 0x7fffffffll) && (L.unionBase + M2 <= P.ws_ints);
  if (!pairOk) return;
  int base = btotPrefix(L.btot, bid);
  int EK = btotPrefix(L.btot, SG);
  int m2i = (int)M2;
  int chunkP = (m2i + SG - 1)/SG;
  int pstart = bid*chunkP; if (pstart > m2i) pstart = m2i;
  int pend = pstart + chunkP; if (pend > m2i) pend = m2i;
  size_t eBase = (size_t)M * (size_t)P.d;
  bool outOk = (eBase + 3ull*(size_t)EK <= (size_t)P.out_size);
  int running2 = base;
  for (int t0 = pstart; t0 < pend; t0 += BLOCK) {
    int i = t0 + tid;
    int c = 0, kept = 0, a = 0, b2 = 0;
    if (i < pend) {
      c = L.pairCnt[i];
      a = i / M; b2 = i % M;
      kept = (c > 0 && a != b2) ? 1 : 0;
    }
    lds[tid] = kept; __syncthreads();
    for (int off = 1; off < 256; off <<= 1) {
      int t = (tid >= off) ? lds[tid-off] : 0; __syncthreads();
      lds[tid] += t; __syncthreads();
    }
    int incl = lds[tid], tot = lds[255];
    if (kept && outOk) {
      int j2 = running2 + incl - 1;
      P.out[eBase + (size_t)j2] = (float)a;
      P.out[eBase + (size_t)EK + (size_t)j2] = (float)b2;
      P.out[eBase + 2ull*(size_t)EK + (size_t)j2] = (float)c;
    }
    running2 += tot;
    __syncthreads();
  }
}

__global__ __launch_bounds__(BLOCK) void k_xpool(KParams P) {
  Lay L = mklay(P.ws, P.n, P.e);
  int gid = blockIdx.x*BLOCK + threadIdx.x;
  int lane = gid & 63, gwv = gid >> 6;
  int M = L.cnts[2];
  int d4 = P.d >> 2;
  size_t eBase = (size_t)M * (size_t)P.d;
  if (eBase > (size_t)P.out_size) return;
  for (int v = gwv; v < P.n; v += NWVE) {
    if (L.mis[v]) {
      int p = L.misPre[v];
      float sc = L.score[v];
      const float4* xr = (const float4*)(P.x + (size_t)v*P.d);
      float4* outr = (float4*)P.out + (size_t)p*d4;
      for (int q = lane; q < d4; q += 64) {
        float4 xv = xr[q];
        outr[q] = make_float4(xv.x*sc, xv.y*sc, xv.z*sc, xv.w*sc);
      }
    }
  }
}

extern "C" void kernel_launch(void* const* d_in, const int* in_sizes, int n_in,
                              void* d_out, int out_size, void* d_ws, size_t ws_size,
                              hipStream_t stream) {
  KParams P;
  P.x  = (const float*)d_in[0];
  P.ei = (const int*)d_in[1];
  P.w  = (const float*)d_in[2];
  P.bb = (const float*)d_in[3];
  P.out = (float*)d_out;
  P.d = in_sizes[2];            // 256
  P.n = in_sizes[0] / P.d;      // 100000
  P.e = in_sizes[1] / 2;        // 1600000
  P.out_size = out_size;
  P.ws = (int*)d_ws;
  P.ws_ints = (long long)(ws_size / 4);
  const int nblk = (P.n + BLOCK - 1) / BLOCK;

  k_score <<<EGRID, BLOCK, 0, stream>>>(P);
  k_degree<<<EGRID, BLOCK, 0, stream>>>(P);
  k_scan1 <<<SG,    BLOCK, 0, stream>>>(P);
  k_scan3 <<<SG,    BLOCK, 0, stream>>>(P);
  k_csr   <<<EGRID, BLOCK, 0, stream>>>(P);
  k_keygen<<<nblk,  BLOCK, 0, stream>>>(P);
  for (int pass = 0; pass < 4; ++pass) {
    k_sort_local  <<<SG, BLOCK, 0, stream>>>(P, pass);
    k_sort_scan1  <<<64, BLOCK, 0, stream>>>(P);
    k_sort_scatter<<<SG, BLOCK, 0, stream>>>(P, pass);
  }
  k_rankinit<<<nblk, BLOCK, 0, stream>>>(P);
  for (int t = 0; t < DENSE_ITERS; ++t) {
    k_dmin <<<nblk, BLOCK, 0, stream>>>(P, t);
    k_dsel <<<nblk, BLOCK, 0, stream>>>(P, t);
    k_dor  <<<nblk, BLOCK, 0, stream>>>(P, t);
    k_drb  <<<nblk, BLOCK, 0, stream>>>(P, t);
  }
  k_tcomp1 <<<SG,   BLOCK, 0, stream>>>(P);
  k_tcomp3 <<<SG,   BLOCK, 0, stream>>>(P);
  k_tbuild <<<nblk, BLOCK, 0, stream>>>(P);
  k_trounds<<<1,    1024,  0, stream>>>(P);
  k_scanM1<<<SG, BLOCK, 0, stream>>>(P);
  k_fin1  <<<nblk, BLOCK, 0, stream>>>(P);
  k_fin2  <<<nblk, BLOCK, 0, stream>>>(P);
  k_scanM3<<<SG, BLOCK, 0, stream>>>(P);
  k_clus <<<EGRID, BLOCK, 0, stream>>>(P);
  k_pair <<<EGRID, BLOCK, 0, stream>>>(P);
  k_keep1<<<SG,    BLOCK, 0, stream>>>(P);
  k_edges<<<SG,    BLOCK, 0, stream>>>(P);
  k_xpool<<<EGRID, BLOCK, 0, stream>>>(P);
}